// Round 1
// baseline (422.758 us; speedup 1.0000x reference)
//
#include <hip/hip_runtime.h>
#include <cstdint>

// MTNN: static MLP + dyn proj + biRNN(relu) + routed per-trial dot.
// B=512,T=200,SI=100,DI=68,HS=256,HD=128,D=512,K=1. fp32 in, fp32 out.
// R9: k_scan = MFMA recurrence, 16 batch rows / 1-wave block, H via LDS.
// R10: kill the DS pipe in k_scan entirely. The D-frag->B-frag H handoff is a
// fixed permutation within 4-lane groups {ln,ln+16,ln+32,ln+48}:
//   consumer (ln,q') hf[c] words = packets j=2c+(q'>>1) of producer lanes
//   q=2(q'&1), 2(q'&1)+1. Realized with v_permlane32_swap_b32 +
//   v_permlane16_swap_b32 (VALU, no LDS): per c, per word w:
//   p32(a=hp[2c].w, b=hp[2c+1].w) -> a=[A0,A1,B0,B1], b=[A2,A3,B2,B3];
//   p16(a,b) -> a=[A0,A2,B0,B2]=w0, b=[A1,A3,B1,B3]=w2.   (quadrants q'=0..3)
// p-reduction shfl_xor(16/32) likewise -> permlane swaps. Zero LDS, zero
// barriers, no lgkmcnt waits in the recurrence.
constexpr int B = 512, T = 200, SI = 100, DI = 68, HS = 256, HD = 128, D = 512;
constexpr int BT = B * T;   // 102400

typedef __attribute__((ext_vector_type(8))) short short8;       // 8 bf16
typedef __attribute__((ext_vector_type(4))) float floatx4;      // MFMA C/D
typedef _Float16 half8 __attribute__((ext_vector_type(8)));     // 8 fp16
typedef _Float16 half2t __attribute__((ext_vector_type(2)));    // fp16 pair
typedef unsigned int uint4v __attribute__((ext_vector_type(4)));

#define DEV __device__ __forceinline__

DEV unsigned short f2bf(float f) {
    unsigned int x = __builtin_bit_cast(unsigned int, f);
    x += 0x7fffu + ((x >> 16) & 1u);   // RNE
    return (unsigned short)(x >> 16);
}
DEV unsigned short f2h(float f) {
    return __builtin_bit_cast(unsigned short, (_Float16)f);
}
DEV half2t u2h2(unsigned int u) { return __builtin_bit_cast(half2t, u); }
DEV unsigned int pkh(float a, float b) {
    return __builtin_bit_cast(unsigned int, __builtin_amdgcn_cvt_pkrtz(a, b));
}
// gfx950 lane swaps (VALU). After p32: a=[a.lo,b.lo], b=[a.hi,b.hi].
// After p16 (per 32-half): a=[a.q0,b.q0|a.q2,b.q2], b=[a.q1,b.q1|a.q3,b.q3].
DEV void pl32swap(unsigned int& a, unsigned int& b) {
    asm("v_permlane32_swap_b32 %0, %1" : "+v"(a), "+v"(b));
}
DEV void pl16swap(unsigned int& a, unsigned int& b) {
    asm("v_permlane16_swap_b32 %0, %1" : "+v"(a), "+v"(b));
}

// ---------------- K0: one-time weight conversion ----------------------------
// wdyn_bf[128][96] bf16 (zero-pad K 68->96) | wih_bf[2][128][128] bf16 |
// whh_h[2][128][128] fp16
__global__ __launch_bounds__(256) void k_prep(
    const float* __restrict__ wdyn,
    const float* __restrict__ wihf, const float* __restrict__ wihb,
    const float* __restrict__ whhf, const float* __restrict__ whhb,
    unsigned short* __restrict__ wdyn_bf, unsigned short* __restrict__ wih_bf,
    unsigned short* __restrict__ whh_h)
{
    int gid = blockIdx.x * 256 + threadIdx.x, gs = gridDim.x * 256;
    for (int i = gid; i < HD * 96; i += gs) {
        int r = i / 96, c = i - r * 96;
        wdyn_bf[i] = (c < DI) ? f2bf(wdyn[r * DI + c]) : 0;
    }
    for (int i = gid; i < 2 * HD * HD; i += gs) {
        const float* src = (i < HD * HD) ? wihf : wihb;
        wih_bf[i] = f2bf(src[i & (HD * HD - 1)]);
    }
    for (int i = gid; i < 2 * HD * HD; i += gs) {
        const float* src = (i < HD * HD) ? whhf : whhb;
        whh_h[i] = f2h(src[i & (HD * HD - 1)]);
    }
}

// ---------------- K1: static branch + static segment of routed dot ----------
__global__ __launch_bounds__(256) void k_static(
    const float* __restrict__ xs_g, const float* __restrict__ w1,
    const float* __restrict__ b1, const float* __restrict__ w2,
    const float* __restrict__ b2, const int* __restrict__ norder,
    const float* __restrict__ nw, const float* __restrict__ nb,
    float* __restrict__ statd)
{
    __shared__ __align__(16) float xs[SI];
    __shared__ __align__(16) float s1[HS];
    __shared__ __align__(16) float red[256];
    int b = blockIdx.x, t = threadIdx.x;
    if (t < SI) xs[t] = xs_g[b * SI + t];
    __syncthreads();
    float a = b1[t];
    const float4* w = (const float4*)(w1 + t * SI);
    const float4* xp4 = (const float4*)xs;
    #pragma unroll
    for (int i = 0; i < SI / 4; ++i) {
        float4 ww = w[i]; float4 xx = xp4[i];
        a += xx.x * ww.x + xx.y * ww.y + xx.z * ww.z + xx.w * ww.w;
    }
    s1[t] = fmaxf(a, 0.f);
    __syncthreads();
    float a2 = b2[t];
    const float4* w2p = (const float4*)(w2 + t * HS);
    const float4* s1p = (const float4*)s1;
    #pragma unroll 8
    for (int i = 0; i < HS / 4; ++i) {
        float4 ww = w2p[i]; float4 s = s1p[i];
        a2 += s.x * ww.x + s.y * ww.y + s.z * ww.z + s.w * ww.w;
    }
    float sv = fmaxf(a2, 0.f);
    int n = norder[b];
    red[t] = sv * nw[(size_t)n * D + t];
    __syncthreads();
    for (int s = 128; s > 0; s >>= 1) {
        if (t < s) red[t] += red[t + s];
        __syncthreads();
    }
    if (t == 0) statd[b] = red[0] + nb[n];
}

// ---------------- K2: d + ih-projection via MFMA (prepped weights) ----------
__global__ __launch_bounds__(256) void k_dxw(
    const float* __restrict__ xd,
    const unsigned short* __restrict__ wdyn_bf, const float* __restrict__ bdyn,
    const unsigned short* __restrict__ wih_bf,
    const float* __restrict__ bihf, const float* __restrict__ bhhf,
    const float* __restrict__ bihb, const float* __restrict__ bhhb,
    unsigned short* __restrict__ xw)
{
    __shared__ __align__(16) unsigned short xb[64][104];  // x bf16, K 0..95 (+pad)
    __shared__ __align__(16) unsigned short dl[64][136];  // d bf16, 128 cols (+pad)
    int tid = threadIdx.x;
    int R0 = blockIdx.x * 64;
    for (int i = tid; i < 64 * 104; i += 256) ((unsigned short*)xb)[i] = 0;
    __syncthreads();
    for (int i = tid; i < 64 * DI; i += 256) {
        int r = i / DI, c = i - r * DI;
        xb[r][c] = f2bf(xd[(size_t)(R0 + r) * DI + c]);
    }
    __syncthreads();

    int lane = tid & 63, w = tid >> 6;
    int ln = lane & 15, q = lane >> 4;

    // ---- P2 ----
    short8 af[3];
    #pragma unroll
    for (int c = 0; c < 3; ++c)
        af[c] = *(const short8*)&xb[w * 16 + ln][c * 32 + q * 8];
    #pragma unroll
    for (int j = 0; j < 8; ++j) {
        int n = j * 16 + ln;
        floatx4 a = {0.f, 0.f, 0.f, 0.f};
        #pragma unroll
        for (int c = 0; c < 3; ++c) {
            short8 bf = *(const short8*)(wdyn_bf + (size_t)n * 96 + c * 32 + q * 8);
            a = __builtin_amdgcn_mfma_f32_16x16x32_bf16(af[c], bf, a, 0, 0, 0);
        }
        float bd = bdyn[n];
        #pragma unroll
        for (int r = 0; r < 4; ++r) {
            float v = fmaxf(a[r] + bd, 0.f);              // C/D: row=q*4+r, col=n
            dl[w * 16 + q * 4 + r][n] = f2bf(v);
        }
    }
    __syncthreads();

    // ---- P3 (both directions) ----
    short8 df[4];
    #pragma unroll
    for (int c = 0; c < 4; ++c)
        df[c] = *(const short8*)&dl[w * 16 + ln][c * 32 + q * 8];
    #pragma unroll
    for (int z = 0; z < 2; ++z) {
        const float* bi = z ? bihb : bihf;
        const float* bh = z ? bhhb : bhhf;
        const unsigned short* wih = wih_bf + (size_t)z * HD * HD;
        unsigned short* outp = xw + (size_t)z * BT * HD;
        #pragma unroll
        for (int j = 0; j < 8; ++j) {
            int n = j * 16 + ln;
            floatx4 a = {0.f, 0.f, 0.f, 0.f};
            #pragma unroll
            for (int c = 0; c < 4; ++c) {
                short8 bf = *(const short8*)(wih + (size_t)n * HD + c * 32 + q * 8);
                a = __builtin_amdgcn_mfma_f32_16x16x32_bf16(df[c], bf, a, 0, 0, 0);
            }
            float bias = bi[n] + bh[n];
            #pragma unroll
            for (int r = 0; r < 4; ++r) {
                int row = R0 + w * 16 + q * 4 + r;
                outp[(size_t)row * HD + n] = f2h(a[r] + bias);  // fp16, no relu
            }
        }
    }
}

// ---------------- K3: MFMA recurrence, 16 rows per 1-wave block -------------
// 64 blocks x 64 thr. dir = bid>>5, b0 = (bid&31)*16.
// Step: H_t[o][row] = relu(XW_t[o][row] + Whh H_{t-1}), o-tiles j=0..7,
// K-chunks c=0..3. A=Whh (fp16 frags, loaded once), B=H in registers:
// the D->B handoff is pure permlane swaps (see header). No LDS, no DS ops.
__global__ __launch_bounds__(64, 1) void k_scan(
    const unsigned short* __restrict__ xw, const unsigned short* __restrict__ whh_h,
    const int* __restrict__ norder, const float* __restrict__ nw,
    float* __restrict__ accf, float* __restrict__ accb)
{
    int l = threadIdx.x, ln = l & 15, q = l >> 4;
    int dir = blockIdx.x >> 5, b0 = (blockIdx.x & 31) * 16;
    const unsigned short* whh = whh_h + (size_t)dir * HD * HD;
    float* acc = dir ? accb : accf;
    int segoff = dir ? (HS + HD) : HS;   // 384 : 256

    // A-frags: Whh[o = j*16+ln][k = c*32+q*8 .. +7], fp16
    half8 wfr[8][4];
    #pragma unroll
    for (int j = 0; j < 8; ++j)
        #pragma unroll
        for (int c = 0; c < 4; ++c)
            wfr[j][c] = *(const half8*)(whh + (size_t)(j * 16 + ln) * HD + c * 32 + q * 8);

    // routed weights for this lane's (row=ln, o=j*16+q*4..+3)
    int nrow = norder[b0 + ln];
    float4 wnl[8];
    #pragma unroll
    for (int j = 0; j < 8; ++j)
        wnl[j] = *(const float4*)(nw + (size_t)nrow * D + segoff + j * 16 + q * 4);

    // H_0 = 0 -> B-frags start at zero
    half8 hf[4];
    uint4v zz = {0u, 0u, 0u, 0u};
    #pragma unroll
    for (int c = 0; c < 4; ++c) hf[c] = __builtin_bit_cast(half8, zz);

    // xw base for this lane's batch row; C-init values o=j*16+q*4..+3
    const unsigned short* xp = xw + ((size_t)dir * BT + (size_t)(b0 + ln) * T) * HD;
    float* accp = acc + (size_t)(b0 + ln) * T;
    int t = dir ? (T - 1) : 0, dt = dir ? -1 : 1;
    uint2 xc[8], xn[8];
    #pragma unroll
    for (int j = 0; j < 8; ++j)
        xc[j] = *(const uint2*)(xp + (size_t)t * HD + j * 16 + q * 4);
    #pragma unroll
    for (int j = 0; j < 8; ++j)
        xn[j] = *(const uint2*)(xp + (size_t)(t + dt) * HD + j * 16 + q * 4);

    for (int step = 0; step < T; ++step) {
        // prefetch xw for step+2 (issue early, consumed 2 steps later)
        int t2 = t + 2 * dt;
        uint2 px[8];
        if (step + 2 < T) {
            #pragma unroll
            for (int j = 0; j < 8; ++j)
                px[j] = *(const uint2*)(xp + (size_t)t2 * HD + j * 16 + q * 4);
        } else {
            #pragma unroll
            for (int j = 0; j < 8; ++j) px[j] = xn[j];
        }

        // 8 o-tiles: C-init from xw, 4 chained mfma each; relu + pack + dot
        uint2 hpbuf[8];
        float p = 0.f;
        #pragma unroll
        for (int j = 0; j < 8; ++j) {
            half2t lo = u2h2(xc[j].x), hi = u2h2(xc[j].y);
            floatx4 a = {(float)lo[0], (float)lo[1], (float)hi[0], (float)hi[1]};
            #pragma unroll
            for (int c = 0; c < 4; ++c)
                a = __builtin_amdgcn_mfma_f32_16x16x32_f16(wfr[j][c], hf[c], a, 0, 0, 0);
            float r0 = fmaxf(a[0], 0.f), r1 = fmaxf(a[1], 0.f);
            float r2 = fmaxf(a[2], 0.f), r3 = fmaxf(a[3], 0.f);
            uint2 hp;
            hp.x = pkh(r0, r1);
            hp.y = pkh(r2, r3);
            hpbuf[j] = hp;
            float4 wn4 = wnl[j];
            p += r0 * wn4.x + r1 * wn4.y + r2 * wn4.z + r3 * wn4.w;
        }

        // D-frag -> next-step B-frag: permlane swaps within {ln,ln+16,+32,+48}.
        // hf[c] words: [w0,w1,w2,w3] = [src0.x, src0.y, src1.x, src1.y] where
        // src0/src1 = lanes q=2(q'&1), +1 of packet j=2c+(q'>>1).
        #pragma unroll
        for (int c = 0; c < 4; ++c) {
            unsigned int ax = hpbuf[2 * c].x, bx = hpbuf[2 * c + 1].x;
            unsigned int ay = hpbuf[2 * c].y, by = hpbuf[2 * c + 1].y;
            pl32swap(ax, bx);   // ax=[A0,A1,B0,B1] bx=[A2,A3,B2,B3]
            pl16swap(ax, bx);   // ax=[A0,A2,B0,B2]=w0  bx=[A1,A3,B1,B3]=w2
            pl32swap(ay, by);
            pl16swap(ay, by);   // ay=w1, by=w3
            uint4v hw = {ax, ay, bx, by};
            hf[c] = __builtin_bit_cast(half8, hw);
        }

        // reduce p over q (lanes ln, ln+16, ln+32, ln+48) via permlane swaps
        unsigned int pa = __builtin_bit_cast(unsigned int, p), pb = pa;
        pl32swap(pa, pb);
        float ps = __builtin_bit_cast(float, pa) + __builtin_bit_cast(float, pb);
        unsigned int pc = __builtin_bit_cast(unsigned int, ps), pd = pc;
        pl16swap(pc, pd);
        float ptot = __builtin_bit_cast(float, pc) + __builtin_bit_cast(float, pd);
        if (l < 16) accp[t] = ptot;

        #pragma unroll
        for (int j = 0; j < 8; ++j) { xc[j] = xn[j]; xn[j] = px[j]; }
        t += dt;
    }
}

// ---------------- K4: out = relu(statd[b] + accf + accb) -> FP32 ------------
__global__ __launch_bounds__(256) void k_final(
    const float* __restrict__ statd, const float* __restrict__ accf,
    const float* __restrict__ accb, float* __restrict__ out)
{
    int idx = blockIdx.x * 256 + threadIdx.x;
    if (idx < BT) {
        int b = idx / T;
        out[idx] = fmaxf(statd[b] + accf[idx] + accb[idx], 0.f);
    }
}

extern "C" void kernel_launch(void* const* d_in, const int* in_sizes, int n_in,
                              void* d_out, int out_size, void* d_ws, size_t ws_size,
                              hipStream_t stream)
{
    const float* x_static  = (const float*)d_in[0];
    const float* x_dynamic = (const float*)d_in[1];
    const int*   norder    = (const int*)d_in[2];
    const float* w_s1   = (const float*)d_in[3];
    const float* b_s1   = (const float*)d_in[4];
    const float* w_s2   = (const float*)d_in[5];
    const float* b_s2   = (const float*)d_in[6];
    const float* w_dyn  = (const float*)d_in[7];
    const float* b_dyn  = (const float*)d_in[8];
    const float* w_ih_f = (const float*)d_in[9];
    const float* w_hh_f = (const float*)d_in[10];
    const float* b_ih_f = (const float*)d_in[11];
    const float* b_hh_f = (const float*)d_in[12];
    const float* w_ih_b = (const float*)d_in[13];
    const float* w_hh_b = (const float*)d_in[14];
    const float* b_ih_b = (const float*)d_in[15];
    const float* b_hh_b = (const float*)d_in[16];
    const float* nw     = (const float*)d_in[17];
    const float* nb     = (const float*)d_in[18];
    float* out = (float*)d_out;

    // ws: statd 2KB | accf 400KB | accb 400KB | xw fp16 52.4MB | prepped wts
    char* ws = (char*)d_ws;
    float* statd = (float*)ws;
    float* accf  = (float*)(ws + 2048);
    float* accb  = (float*)(ws + 2048 + (size_t)BT * 4);
    unsigned short* xw = (unsigned short*)(ws + 2048 + (size_t)BT * 8);
    size_t xw_bytes = (size_t)2 * BT * HD * 2;   // 52.4 MB
    unsigned short* wdyn_bf = (unsigned short*)(ws + 2048 + (size_t)BT * 8 + xw_bytes);
    unsigned short* wih_bf  = wdyn_bf + HD * 96;
    unsigned short* whh_h   = wih_bf + 2 * HD * HD;

    hipLaunchKernelGGL(k_prep, dim3(64), dim3(256), 0, stream,
                       w_dyn, w_ih_f, w_ih_b, w_hh_f, w_hh_b,
                       wdyn_bf, wih_bf, whh_h);
    hipLaunchKernelGGL(k_static, dim3(B), dim3(256), 0, stream,
                       x_static, w_s1, b_s1, w_s2, b_s2, norder, nw, nb, statd);
    hipLaunchKernelGGL(k_dxw, dim3(BT / 64), dim3(256), 0, stream,
                       x_dynamic, wdyn_bf, b_dyn, wih_bf,
                       b_ih_f, b_hh_f, b_ih_b, b_hh_b, xw);
    hipLaunchKernelGGL(k_scan, dim3(64), dim3(64), 0, stream,
                       xw, whh_h, norder, nw, accf, accb);
    hipLaunchKernelGGL(k_final, dim3((BT + 255) / 256), dim3(256), 0, stream,
                       statd, accf, accb, out);
}

// Round 3
// 412.827 us; speedup vs baseline: 1.0241x; 1.0241x over previous
//
#include <hip/hip_runtime.h>
#include <cstdint>

// MTNN: static MLP + dyn proj + biRNN(relu) + routed per-trial dot.
// B=512,T=200,SI=100,DI=68,HS=256,HD=128,D=512,K=1. fp32 in, fp32 out.
// R10 (passed, 190us k_scan): H handoff via permlane swaps, zero LDS; xw
// prefetch via register ROTATION xc<-xn<-px. Rotation's register moves force
// a near-vmcnt(0) wait on the current step's loads every step -> ~1700cyc
// exposed vmem latency per step.
// R11 (failed): global_load_lds bulk staging -- wrong numerics, reverted.
// R12: R10 structure, but xw prefetch = 4-phase STATIC register buffers
// (xb0..xb3, chunk of 4 steps fully unrolled, re-issue right after consume).
// No moves -> compiler emits counted vmcnt(N); each buffer has 3 compute
// steps (~1200cyc) of latency cover. No LDS, no inline-asm waits.
constexpr int B = 512, T = 200, SI = 100, DI = 68, HS = 256, HD = 128, D = 512;
constexpr int BT = B * T;   // 102400

typedef __attribute__((ext_vector_type(8))) short short8;       // 8 bf16
typedef __attribute__((ext_vector_type(4))) float floatx4;      // MFMA C/D
typedef _Float16 half8 __attribute__((ext_vector_type(8)));     // 8 fp16
typedef _Float16 half2t __attribute__((ext_vector_type(2)));    // fp16 pair
typedef unsigned int uint4v __attribute__((ext_vector_type(4)));

#define DEV __device__ __forceinline__

DEV unsigned short f2bf(float f) {
    unsigned int x = __builtin_bit_cast(unsigned int, f);
    x += 0x7fffu + ((x >> 16) & 1u);   // RNE
    return (unsigned short)(x >> 16);
}
DEV unsigned short f2h(float f) {
    return __builtin_bit_cast(unsigned short, (_Float16)f);
}
DEV half2t u2h2(unsigned int u) { return __builtin_bit_cast(half2t, u); }
DEV unsigned int pkh(float a, float b) {
    return __builtin_bit_cast(unsigned int, __builtin_amdgcn_cvt_pkrtz(a, b));
}
// gfx950 lane swaps (VALU). After p32: a=[a.lo,b.lo], b=[a.hi,b.hi].
// After p16 (per 32-half): a=[a.q0,b.q0|a.q2,b.q2], b=[a.q1,b.q1|a.q3,b.q3].
DEV void pl32swap(unsigned int& a, unsigned int& b) {
    asm("v_permlane32_swap_b32 %0, %1" : "+v"(a), "+v"(b));
}
DEV void pl16swap(unsigned int& a, unsigned int& b) {
    asm("v_permlane16_swap_b32 %0, %1" : "+v"(a), "+v"(b));
}

// ---------------- K0: one-time weight conversion ----------------------------
// wdyn_bf[128][96] bf16 (zero-pad K 68->96) | wih_bf[2][128][128] bf16 |
// whh_h[2][128][128] fp16
__global__ __launch_bounds__(256) void k_prep(
    const float* __restrict__ wdyn,
    const float* __restrict__ wihf, const float* __restrict__ wihb,
    const float* __restrict__ whhf, const float* __restrict__ whhb,
    unsigned short* __restrict__ wdyn_bf, unsigned short* __restrict__ wih_bf,
    unsigned short* __restrict__ whh_h)
{
    int gid = blockIdx.x * 256 + threadIdx.x, gs = gridDim.x * 256;
    for (int i = gid; i < HD * 96; i += gs) {
        int r = i / 96, c = i - r * 96;
        wdyn_bf[i] = (c < DI) ? f2bf(wdyn[r * DI + c]) : 0;
    }
    for (int i = gid; i < 2 * HD * HD; i += gs) {
        const float* src = (i < HD * HD) ? wihf : wihb;
        wih_bf[i] = f2bf(src[i & (HD * HD - 1)]);
    }
    for (int i = gid; i < 2 * HD * HD; i += gs) {
        const float* src = (i < HD * HD) ? whhf : whhb;
        whh_h[i] = f2h(src[i & (HD * HD - 1)]);
    }
}

// ---------------- K1: static branch + static segment of routed dot ----------
__global__ __launch_bounds__(256) void k_static(
    const float* __restrict__ xs_g, const float* __restrict__ w1,
    const float* __restrict__ b1, const float* __restrict__ w2,
    const float* __restrict__ b2, const int* __restrict__ norder,
    const float* __restrict__ nw, const float* __restrict__ nb,
    float* __restrict__ statd)
{
    __shared__ __align__(16) float xs[SI];
    __shared__ __align__(16) float s1[HS];
    __shared__ __align__(16) float red[256];
    int b = blockIdx.x, t = threadIdx.x;
    if (t < SI) xs[t] = xs_g[b * SI + t];
    __syncthreads();
    float a = b1[t];
    const float4* w = (const float4*)(w1 + t * SI);
    const float4* xp4 = (const float4*)xs;
    #pragma unroll
    for (int i = 0; i < SI / 4; ++i) {
        float4 ww = w[i]; float4 xx = xp4[i];
        a += xx.x * ww.x + xx.y * ww.y + xx.z * ww.z + xx.w * ww.w;
    }
    s1[t] = fmaxf(a, 0.f);
    __syncthreads();
    float a2 = b2[t];
    const float4* w2p = (const float4*)(w2 + t * HS);
    const float4* s1p = (const float4*)s1;
    #pragma unroll 8
    for (int i = 0; i < HS / 4; ++i) {
        float4 ww = w2p[i]; float4 s = s1p[i];
        a2 += s.x * ww.x + s.y * ww.y + s.z * ww.z + s.w * ww.w;
    }
    float sv = fmaxf(a2, 0.f);
    int n = norder[b];
    red[t] = sv * nw[(size_t)n * D + t];
    __syncthreads();
    for (int s = 128; s > 0; s >>= 1) {
        if (t < s) red[t] += red[t + s];
        __syncthreads();
    }
    if (t == 0) statd[b] = red[0] + nb[n];
}

// ---------------- K2: d + ih-projection via MFMA (prepped weights) ----------
__global__ __launch_bounds__(256) void k_dxw(
    const float* __restrict__ xd,
    const unsigned short* __restrict__ wdyn_bf, const float* __restrict__ bdyn,
    const unsigned short* __restrict__ wih_bf,
    const float* __restrict__ bihf, const float* __restrict__ bhhf,
    const float* __restrict__ bihb, const float* __restrict__ bhhb,
    unsigned short* __restrict__ xw)
{
    __shared__ __align__(16) unsigned short xb[64][104];  // x bf16, K 0..95 (+pad)
    __shared__ __align__(16) unsigned short dl[64][136];  // d bf16, 128 cols (+pad)
    int tid = threadIdx.x;
    int R0 = blockIdx.x * 64;
    for (int i = tid; i < 64 * 104; i += 256) ((unsigned short*)xb)[i] = 0;
    __syncthreads();
    for (int i = tid; i < 64 * DI; i += 256) {
        int r = i / DI, c = i - r * DI;
        xb[r][c] = f2bf(xd[(size_t)(R0 + r) * DI + c]);
    }
    __syncthreads();

    int lane = tid & 63, w = tid >> 6;
    int ln = lane & 15, q = lane >> 4;

    // ---- P2 ----
    short8 af[3];
    #pragma unroll
    for (int c = 0; c < 3; ++c)
        af[c] = *(const short8*)&xb[w * 16 + ln][c * 32 + q * 8];
    #pragma unroll
    for (int j = 0; j < 8; ++j) {
        int n = j * 16 + ln;
        floatx4 a = {0.f, 0.f, 0.f, 0.f};
        #pragma unroll
        for (int c = 0; c < 3; ++c) {
            short8 bf = *(const short8*)(wdyn_bf + (size_t)n * 96 + c * 32 + q * 8);
            a = __builtin_amdgcn_mfma_f32_16x16x32_bf16(af[c], bf, a, 0, 0, 0);
        }
        float bd = bdyn[n];
        #pragma unroll
        for (int r = 0; r < 4; ++r) {
            float v = fmaxf(a[r] + bd, 0.f);              // C/D: row=q*4+r, col=n
            dl[w * 16 + q * 4 + r][n] = f2bf(v);
        }
    }
    __syncthreads();

    // ---- P3 (both directions) ----
    short8 df[4];
    #pragma unroll
    for (int c = 0; c < 4; ++c)
        df[c] = *(const short8*)&dl[w * 16 + ln][c * 32 + q * 8];
    #pragma unroll
    for (int z = 0; z < 2; ++z) {
        const float* bi = z ? bihb : bihf;
        const float* bh = z ? bhhb : bhhf;
        const unsigned short* wih = wih_bf + (size_t)z * HD * HD;
        unsigned short* outp = xw + (size_t)z * BT * HD;
        #pragma unroll
        for (int j = 0; j < 8; ++j) {
            int n = j * 16 + ln;
            floatx4 a = {0.f, 0.f, 0.f, 0.f};
            #pragma unroll
            for (int c = 0; c < 4; ++c) {
                short8 bf = *(const short8*)(wih + (size_t)n * HD + c * 32 + q * 8);
                a = __builtin_amdgcn_mfma_f32_16x16x32_bf16(df[c], bf, a, 0, 0, 0);
            }
            float bias = bi[n] + bh[n];
            #pragma unroll
            for (int r = 0; r < 4; ++r) {
                int row = R0 + w * 16 + q * 4 + r;
                outp[(size_t)row * HD + n] = f2h(a[r] + bias);  // fp16, no relu
            }
        }
    }
}

// ---------------- K3: MFMA recurrence, 16 rows per 1-wave block -------------
// 64 blocks x 64 thr. dir = bid>>5, b0 = (bid&31)*16.
// Step: H_t[o][row] = relu(XW_t[o][row] + Whh H_{t-1}), o-tiles j=0..7,
// K-chunks c=0..3. A=Whh (fp16 frags, loaded once), B=H in registers via
// permlane-swap handoff (no LDS). xw prefetch: 4 static register buffers,
// chunk of 4 steps unrolled, each buffer re-issued right after consumption
// (3 steps of latency cover, no rotation moves).
__global__ __launch_bounds__(64, 1) void k_scan(
    const unsigned short* __restrict__ xw, const unsigned short* __restrict__ whh_h,
    const int* __restrict__ norder, const float* __restrict__ nw,
    float* __restrict__ accf, float* __restrict__ accb)
{
    int l = threadIdx.x, ln = l & 15, q = l >> 4;
    int dir = blockIdx.x >> 5, b0 = (blockIdx.x & 31) * 16;
    const unsigned short* whh = whh_h + (size_t)dir * HD * HD;
    float* acc = dir ? accb : accf;
    int segoff = dir ? (HS + HD) : HS;   // 384 : 256

    // A-frags: Whh[o = j*16+ln][k = c*32+q*8 .. +7], fp16
    half8 wfr[8][4];
    #pragma unroll
    for (int j = 0; j < 8; ++j)
        #pragma unroll
        for (int c = 0; c < 4; ++c)
            wfr[j][c] = *(const half8*)(whh + (size_t)(j * 16 + ln) * HD + c * 32 + q * 8);

    // routed weights for this lane's (row=ln, o=j*16+q*4..+3)
    int nrow = norder[b0 + ln];
    float4 wnl[8];
    #pragma unroll
    for (int j = 0; j < 8; ++j)
        wnl[j] = *(const float4*)(nw + (size_t)nrow * D + segoff + j * 16 + q * 4);

    // H_0 = 0 -> B-frags start at zero
    half8 hf[4];
    uint4v zz = {0u, 0u, 0u, 0u};
    #pragma unroll
    for (int c = 0; c < 4; ++c) hf[c] = __builtin_bit_cast(half8, zz);

    const unsigned short* xp = xw + ((size_t)dir * BT + (size_t)(b0 + ln) * T) * HD;
    float* accp = acc + (size_t)(b0 + ln) * T;
    int tstart = dir ? (T - 1) : 0, dt = dir ? -1 : 1;

    uint2 xb0[8], xb1[8], xb2[8], xb3[8];
    auto ld = [&](uint2 (&xb)[8], int idx) {
        const unsigned short* pp = xp + (size_t)(tstart + dt * idx) * HD;
        #pragma unroll
        for (int j = 0; j < 8; ++j)
            xb[j] = *(const uint2*)(pp + j * 16 + q * 4);
    };
    auto step = [&](uint2 (&xc)[8], int idx) {
        int t = tstart + dt * idx;
        // 8 o-tiles: C-init from xw, 4 chained mfma each; relu + pack + dot
        uint2 hpbuf[8];
        float p = 0.f;
        #pragma unroll
        for (int j = 0; j < 8; ++j) {
            half2t lo = u2h2(xc[j].x), hi = u2h2(xc[j].y);
            floatx4 a = {(float)lo[0], (float)lo[1], (float)hi[0], (float)hi[1]};
            #pragma unroll
            for (int cc = 0; cc < 4; ++cc)
                a = __builtin_amdgcn_mfma_f32_16x16x32_f16(wfr[j][cc], hf[cc], a, 0, 0, 0);
            float r0 = fmaxf(a[0], 0.f), r1 = fmaxf(a[1], 0.f);
            float r2 = fmaxf(a[2], 0.f), r3 = fmaxf(a[3], 0.f);
            uint2 hp;
            hp.x = pkh(r0, r1);
            hp.y = pkh(r2, r3);
            hpbuf[j] = hp;
            float4 wn4 = wnl[j];
            p += r0 * wn4.x + r1 * wn4.y + r2 * wn4.z + r3 * wn4.w;
        }
        // D-frag -> next-step B-frag: permlane swaps in {ln,+16,+32,+48}
        #pragma unroll
        for (int cc = 0; cc < 4; ++cc) {
            unsigned int ax = hpbuf[2 * cc].x, bx = hpbuf[2 * cc + 1].x;
            unsigned int ay = hpbuf[2 * cc].y, by = hpbuf[2 * cc + 1].y;
            pl32swap(ax, bx);   // ax=[A0,A1,B0,B1] bx=[A2,A3,B2,B3]
            pl16swap(ax, bx);   // ax=w0, bx=w2
            pl32swap(ay, by);
            pl16swap(ay, by);   // ay=w1, by=w3
            uint4v hw = {ax, ay, bx, by};
            hf[cc] = __builtin_bit_cast(half8, hw);
        }
        // reduce p over q (lanes ln,+16,+32,+48) via permlane swaps
        unsigned int pa = __builtin_bit_cast(unsigned int, p), pb = pa;
        pl32swap(pa, pb);
        float ps = __builtin_bit_cast(float, pa) + __builtin_bit_cast(float, pb);
        unsigned int pc = __builtin_bit_cast(unsigned int, ps), pd = pc;
        pl16swap(pc, pd);
        float ptot = __builtin_bit_cast(float, pc) + __builtin_bit_cast(float, pd);
        if (l < 16) accp[t] = ptot;
    };

    ld(xb0, 0); ld(xb1, 1); ld(xb2, 2); ld(xb3, 3);
    for (int c = 0; c < T / 4 - 1; ++c) {
        int i0 = c * 4;
        step(xb0, i0);     ld(xb0, i0 + 4);
        step(xb1, i0 + 1); ld(xb1, i0 + 5);
        step(xb2, i0 + 2); ld(xb2, i0 + 6);
        step(xb3, i0 + 3); ld(xb3, i0 + 7);
    }
    step(xb0, T - 4);
    step(xb1, T - 3);
    step(xb2, T - 2);
    step(xb3, T - 1);
}

// ---------------- K4: out = relu(statd[b] + accf + accb) -> FP32 ------------
__global__ __launch_bounds__(256) void k_final(
    const float* __restrict__ statd, const float* __restrict__ accf,
    const float* __restrict__ accb, float* __restrict__ out)
{
    int idx = blockIdx.x * 256 + threadIdx.x;
    if (idx < BT) {
        int b = idx / T;
        out[idx] = fmaxf(statd[b] + accf[idx] + accb[idx], 0.f);
    }
}

extern "C" void kernel_launch(void* const* d_in, const int* in_sizes, int n_in,
                              void* d_out, int out_size, void* d_ws, size_t ws_size,
                              hipStream_t stream)
{
    const float* x_static  = (const float*)d_in[0];
    const float* x_dynamic = (const float*)d_in[1];
    const int*   norder    = (const int*)d_in[2];
    const float* w_s1   = (const float*)d_in[3];
    const float* b_s1   = (const float*)d_in[4];
    const float* w_s2   = (const float*)d_in[5];
    const float* b_s2   = (const float*)d_in[6];
    const float* w_dyn  = (const float*)d_in[7];
    const float* b_dyn  = (const float*)d_in[8];
    const float* w_ih_f = (const float*)d_in[9];
    const float* w_hh_f = (const float*)d_in[10];
    const float* b_ih_f = (const float*)d_in[11];
    const float* b_hh_f = (const float*)d_in[12];
    const float* w_ih_b = (const float*)d_in[13];
    const float* w_hh_b = (const float*)d_in[14];
    const float* b_ih_b = (const float*)d_in[15];
    const float* b_hh_b = (const float*)d_in[16];
    const float* nw     = (const float*)d_in[17];
    const float* nb     = (const float*)d_in[18];
    float* out = (float*)d_out;

    // ws: statd 2KB | accf 400KB | accb 400KB | xw fp16 52.4MB | prepped wts
    char* ws = (char*)d_ws;
    float* statd = (float*)ws;
    float* accf  = (float*)(ws + 2048);
    float* accb  = (float*)(ws + 2048 + (size_t)BT * 4);
    unsigned short* xw = (unsigned short*)(ws + 2048 + (size_t)BT * 8);
    size_t xw_bytes = (size_t)2 * BT * HD * 2;   // 52.4 MB
    unsigned short* wdyn_bf = (unsigned short*)(ws + 2048 + (size_t)BT * 8 + xw_bytes);
    unsigned short* wih_bf  = wdyn_bf + HD * 96;
    unsigned short* whh_h   = wih_bf + 2 * HD * HD;

    hipLaunchKernelGGL(k_prep, dim3(64), dim3(256), 0, stream,
                       w_dyn, w_ih_f, w_ih_b, w_hh_f, w_hh_b,
                       wdyn_bf, wih_bf, whh_h);
    hipLaunchKernelGGL(k_static, dim3(B), dim3(256), 0, stream,
                       x_static, w_s1, b_s1, w_s2, b_s2, norder, nw, nb, statd);
    hipLaunchKernelGGL(k_dxw, dim3(BT / 64), dim3(256), 0, stream,
                       x_dynamic, wdyn_bf, b_dyn, wih_bf,
                       b_ih_f, b_hh_f, b_ih_b, b_hh_b, xw);
    hipLaunchKernelGGL(k_scan, dim3(64), dim3(64), 0, stream,
                       xw, whh_h, norder, nw, accf, accb);
    hipLaunchKernelGGL(k_final, dim3((BT + 255) / 256), dim3(256), 0, stream,
                       statd, accf, accb, out);
}

// Round 6
// 401.970 us; speedup vs baseline: 1.0517x; 1.0270x over previous
//
#include <hip/hip_runtime.h>
#include <cstdint>

// MTNN: static MLP + dyn proj + biRNN(relu) + routed per-trial dot.
// B=512,T=200,SI=100,DI=68,HS=256,HD=128,D=512,K=1. fp32 in, fp32 out.
// R9/R10/R12 all ~2200cyc/step in k_scan regardless of H-handoff (LDS vs
// permlane) and prefetch scheme: the invariant cost is the per-j chained-MFMA
// structure (32 MFMAs on one dep chain ~55cyc each).
// R13/R14: cc-major MFMA issue, 8 live accumulators -> FAILED numerics.
// Diagnosis: pl*swap inline asm with "+v","+v" and EQUAL input values
// (p-reduction does pb=pa copy) lets RA coalesce both operands into ONE
// register -> v_permlane32_swap_b32 v5,v5 = garbage. R10/R12 passed by RA
// luck; R13's schedule exposed it (and likely R11's failure too).
// R15: same cc-major structure; permlane swaps via gfx950 BUILTINS
// (__builtin_amdgcn_permlane{16,32}_swap: SSA in/out pair, no aliasing,
// hazard-recognized). Fallback asm uses early-clobber copies.
constexpr int B = 512, T = 200, SI = 100, DI = 68, HS = 256, HD = 128, D = 512;
constexpr int BT = B * T;   // 102400

typedef __attribute__((ext_vector_type(8))) short short8;       // 8 bf16
typedef __attribute__((ext_vector_type(4))) float floatx4;      // MFMA C/D
typedef _Float16 half8 __attribute__((ext_vector_type(8)));     // 8 fp16
typedef _Float16 half2t __attribute__((ext_vector_type(2)));    // fp16 pair
typedef unsigned int uint2v __attribute__((ext_vector_type(2)));
typedef unsigned int uint4v __attribute__((ext_vector_type(4)));

#define DEV __device__ __forceinline__

DEV unsigned short f2bf(float f) {
    unsigned int x = __builtin_bit_cast(unsigned int, f);
    x += 0x7fffu + ((x >> 16) & 1u);   // RNE
    return (unsigned short)(x >> 16);
}
DEV unsigned short f2h(float f) {
    return __builtin_bit_cast(unsigned short, (_Float16)f);
}
DEV half2t u2h2(unsigned int u) { return __builtin_bit_cast(half2t, u); }
DEV unsigned int pkh(float a, float b) {
    return __builtin_bit_cast(unsigned int, __builtin_amdgcn_cvt_pkrtz(a, b));
}
// gfx950 lane swaps (VALU). After p32: a=[a.lo,b.lo], b=[a.hi,b.hi].
// After p16 (per 32-half): a=[a.q0,b.q0|a.q2,b.q2], b=[a.q1,b.q1|a.q3,b.q3].
#if __has_builtin(__builtin_amdgcn_permlane32_swap) && __has_builtin(__builtin_amdgcn_permlane16_swap)
DEV void pl32swap(unsigned int& a, unsigned int& b) {
    uint2v r = __builtin_amdgcn_permlane32_swap(a, b, false, false);
    a = r[0]; b = r[1];
}
DEV void pl16swap(unsigned int& a, unsigned int& b) {
    uint2v r = __builtin_amdgcn_permlane16_swap(a, b, false, false);
    a = r[0]; b = r[1];
}
#else
// fallback: force distinct registers via early-clobber copies (the plain
// "+v","+v" form can be RA-coalesced when a==b -> swap-with-self garbage)
DEV void pl32swap(unsigned int& a, unsigned int& b) {
    unsigned int na, nb;
    asm("v_mov_b32 %0, %2\n\t"
        "v_mov_b32 %1, %3\n\t"
        "v_permlane32_swap_b32 %0, %1"
        : "=&v"(na), "=&v"(nb) : "v"(a), "v"(b));
    a = na; b = nb;
}
DEV void pl16swap(unsigned int& a, unsigned int& b) {
    unsigned int na, nb;
    asm("v_mov_b32 %0, %2\n\t"
        "v_mov_b32 %1, %3\n\t"
        "v_permlane16_swap_b32 %0, %1"
        : "=&v"(na), "=&v"(nb) : "v"(a), "v"(b));
    a = na; b = nb;
}
#endif

// ---------------- K0: one-time weight conversion ----------------------------
// wdyn_bf[128][96] bf16 (zero-pad K 68->96) | wih_bf[2][128][128] bf16 |
// whh_h[2][128][128] fp16
__global__ __launch_bounds__(256) void k_prep(
    const float* __restrict__ wdyn,
    const float* __restrict__ wihf, const float* __restrict__ wihb,
    const float* __restrict__ whhf, const float* __restrict__ whhb,
    unsigned short* __restrict__ wdyn_bf, unsigned short* __restrict__ wih_bf,
    unsigned short* __restrict__ whh_h)
{
    int gid = blockIdx.x * 256 + threadIdx.x, gs = gridDim.x * 256;
    for (int i = gid; i < HD * 96; i += gs) {
        int r = i / 96, c = i - r * 96;
        wdyn_bf[i] = (c < DI) ? f2bf(wdyn[r * DI + c]) : 0;
    }
    for (int i = gid; i < 2 * HD * HD; i += gs) {
        const float* src = (i < HD * HD) ? wihf : wihb;
        wih_bf[i] = f2bf(src[i & (HD * HD - 1)]);
    }
    for (int i = gid; i < 2 * HD * HD; i += gs) {
        const float* src = (i < HD * HD) ? whhf : whhb;
        whh_h[i] = f2h(src[i & (HD * HD - 1)]);
    }
}

// ---------------- K1: static branch + static segment of routed dot ----------
__global__ __launch_bounds__(256) void k_static(
    const float* __restrict__ xs_g, const float* __restrict__ w1,
    const float* __restrict__ b1, const float* __restrict__ w2,
    const float* __restrict__ b2, const int* __restrict__ norder,
    const float* __restrict__ nw, const float* __restrict__ nb,
    float* __restrict__ statd)
{
    __shared__ __align__(16) float xs[SI];
    __shared__ __align__(16) float s1[HS];
    __shared__ __align__(16) float red[256];
    int b = blockIdx.x, t = threadIdx.x;
    if (t < SI) xs[t] = xs_g[b * SI + t];
    __syncthreads();
    float a = b1[t];
    const float4* w = (const float4*)(w1 + t * SI);
    const float4* xp4 = (const float4*)xs;
    #pragma unroll
    for (int i = 0; i < SI / 4; ++i) {
        float4 ww = w[i]; float4 xx = xp4[i];
        a += xx.x * ww.x + xx.y * ww.y + xx.z * ww.z + xx.w * ww.w;
    }
    s1[t] = fmaxf(a, 0.f);
    __syncthreads();
    float a2 = b2[t];
    const float4* w2p = (const float4*)(w2 + t * HS);
    const float4* s1p = (const float4*)s1;
    #pragma unroll 8
    for (int i = 0; i < HS / 4; ++i) {
        float4 ww = w2p[i]; float4 s = s1p[i];
        a2 += s.x * ww.x + s.y * ww.y + s.z * ww.z + s.w * ww.w;
    }
    float sv = fmaxf(a2, 0.f);
    int n = norder[b];
    red[t] = sv * nw[(size_t)n * D + t];
    __syncthreads();
    for (int s = 128; s > 0; s >>= 1) {
        if (t < s) red[t] += red[t + s];
        __syncthreads();
    }
    if (t == 0) statd[b] = red[0] + nb[n];
}

// ---------------- K2: d + ih-projection via MFMA (prepped weights) ----------
__global__ __launch_bounds__(256) void k_dxw(
    const float* __restrict__ xd,
    const unsigned short* __restrict__ wdyn_bf, const float* __restrict__ bdyn,
    const unsigned short* __restrict__ wih_bf,
    const float* __restrict__ bihf, const float* __restrict__ bhhf,
    const float* __restrict__ bihb, const float* __restrict__ bhhb,
    unsigned short* __restrict__ xw)
{
    __shared__ __align__(16) unsigned short xb[64][104];  // x bf16, K 0..95 (+pad)
    __shared__ __align__(16) unsigned short dl[64][136];  // d bf16, 128 cols (+pad)
    int tid = threadIdx.x;
    int R0 = blockIdx.x * 64;
    for (int i = tid; i < 64 * 104; i += 256) ((unsigned short*)xb)[i] = 0;
    __syncthreads();
    for (int i = tid; i < 64 * DI; i += 256) {
        int r = i / DI, c = i - r * DI;
        xb[r][c] = f2bf(xd[(size_t)(R0 + r) * DI + c]);
    }
    __syncthreads();

    int lane = tid & 63, w = tid >> 6;
    int ln = lane & 15, q = lane >> 4;

    // ---- P2 ----
    short8 af[3];
    #pragma unroll
    for (int c = 0; c < 3; ++c)
        af[c] = *(const short8*)&xb[w * 16 + ln][c * 32 + q * 8];
    #pragma unroll
    for (int j = 0; j < 8; ++j) {
        int n = j * 16 + ln;
        floatx4 a = {0.f, 0.f, 0.f, 0.f};
        #pragma unroll
        for (int c = 0; c < 3; ++c) {
            short8 bf = *(const short8*)(wdyn_bf + (size_t)n * 96 + c * 32 + q * 8);
            a = __builtin_amdgcn_mfma_f32_16x16x32_bf16(af[c], bf, a, 0, 0, 0);
        }
        float bd = bdyn[n];
        #pragma unroll
        for (int r = 0; r < 4; ++r) {
            float v = fmaxf(a[r] + bd, 0.f);              // C/D: row=q*4+r, col=n
            dl[w * 16 + q * 4 + r][n] = f2bf(v);
        }
    }
    __syncthreads();

    // ---- P3 (both directions) ----
    short8 df[4];
    #pragma unroll
    for (int c = 0; c < 4; ++c)
        df[c] = *(const short8*)&dl[w * 16 + ln][c * 32 + q * 8];
    #pragma unroll
    for (int z = 0; z < 2; ++z) {
        const float* bi = z ? bihb : bihf;
        const float* bh = z ? bhhb : bhhf;
        const unsigned short* wih = wih_bf + (size_t)z * HD * HD;
        unsigned short* outp = xw + (size_t)z * BT * HD;
        #pragma unroll
        for (int j = 0; j < 8; ++j) {
            int n = j * 16 + ln;
            floatx4 a = {0.f, 0.f, 0.f, 0.f};
            #pragma unroll
            for (int c = 0; c < 4; ++c) {
                short8 bf = *(const short8*)(wih + (size_t)n * HD + c * 32 + q * 8);
                a = __builtin_amdgcn_mfma_f32_16x16x32_bf16(df[c], bf, a, 0, 0, 0);
            }
            float bias = bi[n] + bh[n];
            #pragma unroll
            for (int r = 0; r < 4; ++r) {
                int row = R0 + w * 16 + q * 4 + r;
                outp[(size_t)row * HD + n] = f2h(a[r] + bias);  // fp16, no relu
            }
        }
    }
}

// ---------------- K3: MFMA recurrence, 16 rows per 1-wave block -------------
// 64 blocks x 64 thr. dir = bid>>5, b0 = (bid&31)*16.
// Step: H_t[o][row] = relu(XW_t[o][row] + Whh H_{t-1}), o-tiles j=0..7,
// K-chunks cc=0..3. A=Whh (fp16 frags, loaded once), B=H in registers via
// permlane-swap handoff (no LDS). MFMAs issued cc-major across 8 live
// accumulators (8-wide ILP, no serial dependent chains); epilogue separate.
// xw prefetch: 4 static register buffers, re-issued right after consumption.
__global__ __launch_bounds__(64, 1) void k_scan(
    const unsigned short* __restrict__ xw, const unsigned short* __restrict__ whh_h,
    const int* __restrict__ norder, const float* __restrict__ nw,
    float* __restrict__ accf, float* __restrict__ accb)
{
    int l = threadIdx.x, ln = l & 15, q = l >> 4;
    int dir = blockIdx.x >> 5, b0 = (blockIdx.x & 31) * 16;
    const unsigned short* whh = whh_h + (size_t)dir * HD * HD;
    float* acc = dir ? accb : accf;
    int segoff = dir ? (HS + HD) : HS;   // 384 : 256

    // A-frags: Whh[o = j*16+ln][k = cc*32+q*8 .. +7], fp16
    half8 wfr[8][4];
    #pragma unroll
    for (int j = 0; j < 8; ++j)
        #pragma unroll
        for (int c = 0; c < 4; ++c)
            wfr[j][c] = *(const half8*)(whh + (size_t)(j * 16 + ln) * HD + c * 32 + q * 8);

    // routed weights for this lane's (row=ln, o=j*16+q*4..+3)
    int nrow = norder[b0 + ln];
    float4 wnl[8];
    #pragma unroll
    for (int j = 0; j < 8; ++j)
        wnl[j] = *(const float4*)(nw + (size_t)nrow * D + segoff + j * 16 + q * 4);

    // H_0 = 0 -> B-frags start at zero
    half8 hf[4];
    uint4v zz = {0u, 0u, 0u, 0u};
    #pragma unroll
    for (int c = 0; c < 4; ++c) hf[c] = __builtin_bit_cast(half8, zz);

    const unsigned short* xp = xw + ((size_t)dir * BT + (size_t)(b0 + ln) * T) * HD;
    float* accp = acc + (size_t)(b0 + ln) * T;
    int tstart = dir ? (T - 1) : 0, dt = dir ? -1 : 1;

    uint2 xb0[8], xb1[8], xb2[8], xb3[8];
    auto ld = [&](uint2 (&xb)[8], int idx) {
        const unsigned short* pp = xp + (size_t)(tstart + dt * idx) * HD;
        #pragma unroll
        for (int j = 0; j < 8; ++j)
            xb[j] = *(const uint2*)(pp + j * 16 + q * 4);
    };
    auto step = [&](uint2 (&xc)[8], int idx) {
        int t = tstart + dt * idx;
        // C-init for all 8 o-tiles (values o = j*16+q*4..+3 of this row)
        floatx4 a[8];
        #pragma unroll
        for (int j = 0; j < 8; ++j) {
            half2t lo = u2h2(xc[j].x), hi = u2h2(xc[j].y);
            a[j] = floatx4{(float)lo[0], (float)lo[1], (float)hi[0], (float)hi[1]};
        }
        // cc-major MFMA issue: 8 independent accumulators per cc-group.
        // Each mfma's producer is 8 instructions back -> pipe at throughput.
        #pragma unroll
        for (int cc = 0; cc < 4; ++cc)
            #pragma unroll
            for (int j = 0; j < 8; ++j)
                a[j] = __builtin_amdgcn_mfma_f32_16x16x32_f16(wfr[j][cc], hf[cc], a[j], 0, 0, 0);
        // epilogue: relu + pack + routed dot
        uint2 hpbuf[8];
        float p = 0.f;
        #pragma unroll
        for (int j = 0; j < 8; ++j) {
            float r0 = fmaxf(a[j][0], 0.f), r1 = fmaxf(a[j][1], 0.f);
            float r2 = fmaxf(a[j][2], 0.f), r3 = fmaxf(a[j][3], 0.f);
            uint2 hp;
            hp.x = pkh(r0, r1);
            hp.y = pkh(r2, r3);
            hpbuf[j] = hp;
            float4 wn4 = wnl[j];
            p += r0 * wn4.x + r1 * wn4.y + r2 * wn4.z + r3 * wn4.w;
        }
        // D-frag -> next-step B-frag: permlane swaps in {ln,+16,+32,+48}
        #pragma unroll
        for (int cc = 0; cc < 4; ++cc) {
            unsigned int ax = hpbuf[2 * cc].x, bx = hpbuf[2 * cc + 1].x;
            unsigned int ay = hpbuf[2 * cc].y, by = hpbuf[2 * cc + 1].y;
            pl32swap(ax, bx);   // ax=[A0,A1,B0,B1] bx=[A2,A3,B2,B3]
            pl16swap(ax, bx);   // ax=w0, bx=w2
            pl32swap(ay, by);
            pl16swap(ay, by);   // ay=w1, by=w3
            uint4v hw = {ax, ay, bx, by};
            hf[cc] = __builtin_bit_cast(half8, hw);
        }
        // reduce p over q (lanes ln,+16,+32,+48) via permlane swaps
        unsigned int pa = __builtin_bit_cast(unsigned int, p), pb = pa;
        pl32swap(pa, pb);
        float ps = __builtin_bit_cast(float, pa) + __builtin_bit_cast(float, pb);
        unsigned int pc = __builtin_bit_cast(unsigned int, ps), pd = pc;
        pl16swap(pc, pd);
        float ptot = __builtin_bit_cast(float, pc) + __builtin_bit_cast(float, pd);
        if (l < 16) accp[t] = ptot;
    };

    ld(xb0, 0); ld(xb1, 1); ld(xb2, 2); ld(xb3, 3);
    for (int c = 0; c < T / 4 - 1; ++c) {
        int i0 = c * 4;
        step(xb0, i0);     ld(xb0, i0 + 4);
        step(xb1, i0 + 1); ld(xb1, i0 + 5);
        step(xb2, i0 + 2); ld(xb2, i0 + 6);
        step(xb3, i0 + 3); ld(xb3, i0 + 7);
    }
    step(xb0, T - 4);
    step(xb1, T - 3);
    step(xb2, T - 2);
    step(xb3, T - 1);
}

// ---------------- K4: out = relu(statd[b] + accf + accb) -> FP32 ------------
__global__ __launch_bounds__(256) void k_final(
    const float* __restrict__ statd, const float* __restrict__ accf,
    const float* __restrict__ accb, float* __restrict__ out)
{
    int idx = blockIdx.x * 256 + threadIdx.x;
    if (idx < BT) {
        int b = idx / T;
        out[idx] = fmaxf(statd[b] + accf[idx] + accb[idx], 0.f);
    }
}

extern "C" void kernel_launch(void* const* d_in, const int* in_sizes, int n_in,
                              void* d_out, int out_size, void* d_ws, size_t ws_size,
                              hipStream_t stream)
{
    const float* x_static  = (const float*)d_in[0];
    const float* x_dynamic = (const float*)d_in[1];
    const int*   norder    = (const int*)d_in[2];
    const float* w_s1   = (const float*)d_in[3];
    const float* b_s1   = (const float*)d_in[4];
    const float* w_s2   = (const float*)d_in[5];
    const float* b_s2   = (const float*)d_in[6];
    const float* w_dyn  = (const float*)d_in[7];
    const float* b_dyn  = (const float*)d_in[8];
    const float* w_ih_f = (const float*)d_in[9];
    const float* w_hh_f = (const float*)d_in[10];
    const float* b_ih_f = (const float*)d_in[11];
    const float* b_hh_f = (const float*)d_in[12];
    const float* w_ih_b = (const float*)d_in[13];
    const float* w_hh_b = (const float*)d_in[14];
    const float* b_ih_b = (const float*)d_in[15];
    const float* b_hh_b = (const float*)d_in[16];
    const float* nw     = (const float*)d_in[17];
    const float* nb     = (const float*)d_in[18];
    float* out = (float*)d_out;

    // ws: statd 2KB | accf 400KB | accb 400KB | xw fp16 52.4MB | prepped wts
    char* ws = (char*)d_ws;
    float* statd = (float*)ws;
    float* accf  = (float*)(ws + 2048);
    float* accb  = (float*)(ws + 2048 + (size_t)BT * 4);
    unsigned short* xw = (unsigned short*)(ws + 2048 + (size_t)BT * 8);
    size_t xw_bytes = (size_t)2 * BT * HD * 2;   // 52.4 MB
    unsigned short* wdyn_bf = (unsigned short*)(ws + 2048 + (size_t)BT * 8 + xw_bytes);
    unsigned short* wih_bf  = wdyn_bf + HD * 96;
    unsigned short* whh_h   = wih_bf + 2 * HD * HD;

    hipLaunchKernelGGL(k_prep, dim3(64), dim3(256), 0, stream,
                       w_dyn, w_ih_f, w_ih_b, w_hh_f, w_hh_b,
                       wdyn_bf, wih_bf, whh_h);
    hipLaunchKernelGGL(k_static, dim3(B), dim3(256), 0, stream,
                       x_static, w_s1, b_s1, w_s2, b_s2, norder, nw, nb, statd);
    hipLaunchKernelGGL(k_dxw, dim3(BT / 64), dim3(256), 0, stream,
                       x_dynamic, wdyn_bf, b_dyn, wih_bf,
                       b_ih_f, b_hh_f, b_ih_b, b_hh_b, xw);
    hipLaunchKernelGGL(k_scan, dim3(64), dim3(64), 0, stream,
                       xw, whh_h, norder, nw, accf, accb);
    hipLaunchKernelGGL(k_final, dim3((BT + 255) / 256), dim3(256), 0, stream,
                       statd, accf, accb, out);
}

// Round 7
// 316.295 us; speedup vs baseline: 1.3366x; 1.2709x over previous
//
#include <hip/hip_runtime.h>
#include <cstdint>

// MTNN: static MLP + dyn proj + biRNN(relu) + routed per-trial dot.
// B=512,T=200,SI=100,DI=68,HS=256,HD=128,D=512,K=1. fp32 in, fp32 out.
// R15 (passed, k_scan 165.7us): cc-major 8-acc ILP only saved ~240cyc/step.
// Revised model: single wave in-order MFMA issue train (32 mfma x ~19-40cyc
// per-wave spacing) + ~330cyc VALU = ~1990cyc/step critical path. Memory,
// dep-distance, DS-pipe all ruled out (R9-R15). Wall time == per-chain
// latency (64 chains already parallel) -> must split the step across waves.
// R16: 4-wave o-split. Wave w owns j=2w,2w+1 (8 MFMAs + 1/4 epilogue) and
// produces exactly next-step B-frag chunk hf[w] (same permlane math).
// Exchange via double-buffered LDS + RAW s_barrier (no vmcnt drain! keeps
// xw prefetch in flight) with lgkmcnt(0)+sched_barrier fencing. Routed-dot
// partials cross-wave-reduced via LDS; wave0 stores.
constexpr int B = 512, T = 200, SI = 100, DI = 68, HS = 256, HD = 128, D = 512;
constexpr int BT = B * T;   // 102400

typedef __attribute__((ext_vector_type(8))) short short8;       // 8 bf16
typedef __attribute__((ext_vector_type(4))) float floatx4;      // MFMA C/D
typedef _Float16 half8 __attribute__((ext_vector_type(8)));     // 8 fp16
typedef _Float16 half2t __attribute__((ext_vector_type(2)));    // fp16 pair
typedef unsigned int uint2v __attribute__((ext_vector_type(2)));
typedef unsigned int uint4v __attribute__((ext_vector_type(4)));

#define DEV __device__ __forceinline__

DEV unsigned short f2bf(float f) {
    unsigned int x = __builtin_bit_cast(unsigned int, f);
    x += 0x7fffu + ((x >> 16) & 1u);   // RNE
    return (unsigned short)(x >> 16);
}
DEV unsigned short f2h(float f) {
    return __builtin_bit_cast(unsigned short, (_Float16)f);
}
DEV half2t u2h2(unsigned int u) { return __builtin_bit_cast(half2t, u); }
DEV unsigned int pkh(float a, float b) {
    return __builtin_bit_cast(unsigned int, __builtin_amdgcn_cvt_pkrtz(a, b));
}
// gfx950 lane swaps (VALU). After p32: a=[a.lo,b.lo], b=[a.hi,b.hi].
// After p16 (per 32-half): a=[a.q0,b.q0|a.q2,b.q2], b=[a.q1,b.q1|a.q3,b.q3].
#if __has_builtin(__builtin_amdgcn_permlane32_swap) && __has_builtin(__builtin_amdgcn_permlane16_swap)
DEV void pl32swap(unsigned int& a, unsigned int& b) {
    uint2v r = __builtin_amdgcn_permlane32_swap(a, b, false, false);
    a = r[0]; b = r[1];
}
DEV void pl16swap(unsigned int& a, unsigned int& b) {
    uint2v r = __builtin_amdgcn_permlane16_swap(a, b, false, false);
    a = r[0]; b = r[1];
}
#else
DEV void pl32swap(unsigned int& a, unsigned int& b) {
    unsigned int na, nb;
    asm("v_mov_b32 %0, %2\n\t"
        "v_mov_b32 %1, %3\n\t"
        "v_permlane32_swap_b32 %0, %1"
        : "=&v"(na), "=&v"(nb) : "v"(a), "v"(b));
    a = na; b = nb;
}
DEV void pl16swap(unsigned int& a, unsigned int& b) {
    unsigned int na, nb;
    asm("v_mov_b32 %0, %2\n\t"
        "v_mov_b32 %1, %3\n\t"
        "v_permlane16_swap_b32 %0, %1"
        : "=&v"(na), "=&v"(nb) : "v"(a), "v"(b));
    a = na; b = nb;
}
#endif

// ---------------- K0: one-time weight conversion ----------------------------
// wdyn_bf[128][96] bf16 (zero-pad K 68->96) | wih_bf[2][128][128] bf16 |
// whh_h[2][128][128] fp16
__global__ __launch_bounds__(256) void k_prep(
    const float* __restrict__ wdyn,
    const float* __restrict__ wihf, const float* __restrict__ wihb,
    const float* __restrict__ whhf, const float* __restrict__ whhb,
    unsigned short* __restrict__ wdyn_bf, unsigned short* __restrict__ wih_bf,
    unsigned short* __restrict__ whh_h)
{
    int gid = blockIdx.x * 256 + threadIdx.x, gs = gridDim.x * 256;
    for (int i = gid; i < HD * 96; i += gs) {
        int r = i / 96, c = i - r * 96;
        wdyn_bf[i] = (c < DI) ? f2bf(wdyn[r * DI + c]) : 0;
    }
    for (int i = gid; i < 2 * HD * HD; i += gs) {
        const float* src = (i < HD * HD) ? wihf : wihb;
        wih_bf[i] = f2bf(src[i & (HD * HD - 1)]);
    }
    for (int i = gid; i < 2 * HD * HD; i += gs) {
        const float* src = (i < HD * HD) ? whhf : whhb;
        whh_h[i] = f2h(src[i & (HD * HD - 1)]);
    }
}

// ---------------- K1: static branch + static segment of routed dot ----------
__global__ __launch_bounds__(256) void k_static(
    const float* __restrict__ xs_g, const float* __restrict__ w1,
    const float* __restrict__ b1, const float* __restrict__ w2,
    const float* __restrict__ b2, const int* __restrict__ norder,
    const float* __restrict__ nw, const float* __restrict__ nb,
    float* __restrict__ statd)
{
    __shared__ __align__(16) float xs[SI];
    __shared__ __align__(16) float s1[HS];
    __shared__ __align__(16) float red[256];
    int b = blockIdx.x, t = threadIdx.x;
    if (t < SI) xs[t] = xs_g[b * SI + t];
    __syncthreads();
    float a = b1[t];
    const float4* w = (const float4*)(w1 + t * SI);
    const float4* xp4 = (const float4*)xs;
    #pragma unroll
    for (int i = 0; i < SI / 4; ++i) {
        float4 ww = w[i]; float4 xx = xp4[i];
        a += xx.x * ww.x + xx.y * ww.y + xx.z * ww.z + xx.w * ww.w;
    }
    s1[t] = fmaxf(a, 0.f);
    __syncthreads();
    float a2 = b2[t];
    const float4* w2p = (const float4*)(w2 + t * HS);
    const float4* s1p = (const float4*)s1;
    #pragma unroll 8
    for (int i = 0; i < HS / 4; ++i) {
        float4 ww = w2p[i]; float4 s = s1p[i];
        a2 += s.x * ww.x + s.y * ww.y + s.z * ww.z + s.w * ww.w;
    }
    float sv = fmaxf(a2, 0.f);
    int n = norder[b];
    red[t] = sv * nw[(size_t)n * D + t];
    __syncthreads();
    for (int s = 128; s > 0; s >>= 1) {
        if (t < s) red[t] += red[t + s];
        __syncthreads();
    }
    if (t == 0) statd[b] = red[0] + nb[n];
}

// ---------------- K2: d + ih-projection via MFMA (prepped weights) ----------
__global__ __launch_bounds__(256) void k_dxw(
    const float* __restrict__ xd,
    const unsigned short* __restrict__ wdyn_bf, const float* __restrict__ bdyn,
    const unsigned short* __restrict__ wih_bf,
    const float* __restrict__ bihf, const float* __restrict__ bhhf,
    const float* __restrict__ bihb, const float* __restrict__ bhhb,
    unsigned short* __restrict__ xw)
{
    __shared__ __align__(16) unsigned short xb[64][104];  // x bf16, K 0..95 (+pad)
    __shared__ __align__(16) unsigned short dl[64][136];  // d bf16, 128 cols (+pad)
    int tid = threadIdx.x;
    int R0 = blockIdx.x * 64;
    for (int i = tid; i < 64 * 104; i += 256) ((unsigned short*)xb)[i] = 0;
    __syncthreads();
    for (int i = tid; i < 64 * DI; i += 256) {
        int r = i / DI, c = i - r * DI;
        xb[r][c] = f2bf(xd[(size_t)(R0 + r) * DI + c]);
    }
    __syncthreads();

    int lane = tid & 63, w = tid >> 6;
    int ln = lane & 15, q = lane >> 4;

    // ---- P2 ----
    short8 af[3];
    #pragma unroll
    for (int c = 0; c < 3; ++c)
        af[c] = *(const short8*)&xb[w * 16 + ln][c * 32 + q * 8];
    #pragma unroll
    for (int j = 0; j < 8; ++j) {
        int n = j * 16 + ln;
        floatx4 a = {0.f, 0.f, 0.f, 0.f};
        #pragma unroll
        for (int c = 0; c < 3; ++c) {
            short8 bf = *(const short8*)(wdyn_bf + (size_t)n * 96 + c * 32 + q * 8);
            a = __builtin_amdgcn_mfma_f32_16x16x32_bf16(af[c], bf, a, 0, 0, 0);
        }
        float bd = bdyn[n];
        #pragma unroll
        for (int r = 0; r < 4; ++r) {
            float v = fmaxf(a[r] + bd, 0.f);              // C/D: row=q*4+r, col=n
            dl[w * 16 + q * 4 + r][n] = f2bf(v);
        }
    }
    __syncthreads();

    // ---- P3 (both directions) ----
    short8 df[4];
    #pragma unroll
    for (int c = 0; c < 4; ++c)
        df[c] = *(const short8*)&dl[w * 16 + ln][c * 32 + q * 8];
    #pragma unroll
    for (int z = 0; z < 2; ++z) {
        const float* bi = z ? bihb : bihf;
        const float* bh = z ? bhhb : bhhf;
        const unsigned short* wih = wih_bf + (size_t)z * HD * HD;
        unsigned short* outp = xw + (size_t)z * BT * HD;
        #pragma unroll
        for (int j = 0; j < 8; ++j) {
            int n = j * 16 + ln;
            floatx4 a = {0.f, 0.f, 0.f, 0.f};
            #pragma unroll
            for (int c = 0; c < 4; ++c) {
                short8 bf = *(const short8*)(wih + (size_t)n * HD + c * 32 + q * 8);
                a = __builtin_amdgcn_mfma_f32_16x16x32_bf16(df[c], bf, a, 0, 0, 0);
            }
            float bias = bi[n] + bh[n];
            #pragma unroll
            for (int r = 0; r < 4; ++r) {
                int row = R0 + w * 16 + q * 4 + r;
                outp[(size_t)row * HD + n] = f2h(a[r] + bias);  // fp16, no relu
            }
        }
    }
}

// ---------------- K3: MFMA recurrence, 4-wave o-split -----------------------
// 64 blocks x 256 thr (4 waves). dir = bid>>5, b0 = (bid&31)*16.
// Wave w: o-tiles j=2w,2w+1 -> 8 MFMAs/step; produces hf chunk w for next
// step (permlane pair math identical to 1-wave version). Exchange via
// double-buffered LDS + raw s_barrier (no vmcnt drain -> xw prefetch stays
// in flight). Routed-dot p: intra-wave q-reduce -> LDS -> wave0 final.
__global__ __launch_bounds__(256, 1) void k_scan(
    const unsigned short* __restrict__ xw, const unsigned short* __restrict__ whh_h,
    const int* __restrict__ norder, const float* __restrict__ nw,
    float* __restrict__ accf, float* __restrict__ accb)
{
    __shared__ __align__(16) uint4v hxch[2][4][64];   // [parity][chunk][lane]
    __shared__ __align__(16) float  pxch[2][4][16];   // [parity][wave][row]

    int tid = threadIdx.x, w = tid >> 6, l = tid & 63, ln = l & 15, q = l >> 4;
    int dir = blockIdx.x >> 5, b0 = (blockIdx.x & 31) * 16;
    const unsigned short* whh = whh_h + (size_t)dir * HD * HD;
    float* acc = dir ? accb : accf;
    int segoff = dir ? (HS + HD) : HS;   // 384 : 256
    int j0 = 2 * w;                       // this wave's first o-tile

    // A-frags for this wave's 2 o-tiles: Whh[o=(j0+jj)*16+ln][k=c*32+q*8..+7]
    half8 wfr[2][4];
    #pragma unroll
    for (int jj = 0; jj < 2; ++jj)
        #pragma unroll
        for (int c = 0; c < 4; ++c)
            wfr[jj][c] = *(const half8*)(whh + (size_t)((j0 + jj) * 16 + ln) * HD + c * 32 + q * 8);

    // routed weights for this wave's o-range
    int nrow = norder[b0 + ln];
    float4 wnl[2];
    #pragma unroll
    for (int jj = 0; jj < 2; ++jj)
        wnl[jj] = *(const float4*)(nw + (size_t)nrow * D + segoff + (j0 + jj) * 16 + q * 4);

    // H_0 = 0
    half8 hf[4];
    uint4v zz = {0u, 0u, 0u, 0u};
    #pragma unroll
    for (int c = 0; c < 4; ++c) hf[c] = __builtin_bit_cast(half8, zz);

    const unsigned short* xp = xw + ((size_t)dir * BT + (size_t)(b0 + ln) * T) * HD;
    float* accp = acc + (size_t)(b0 + ln) * T;
    int tstart = dir ? (T - 1) : 0, dt = dir ? -1 : 1;

    uint2 xb0[2], xb1[2], xb2[2], xb3[2];
    auto ld = [&](uint2 (&xb)[2], int idx) {
        const unsigned short* pp = xp + (size_t)(tstart + dt * idx) * HD;
        #pragma unroll
        for (int jj = 0; jj < 2; ++jj)
            xb[jj] = *(const uint2*)(pp + (j0 + jj) * 16 + q * 4);
    };
    auto step = [&](uint2 (&xc)[2], int idx) {
        int t = tstart + dt * idx;
        int par = idx & 1;
        // C-init (values o = (j0+jj)*16+q*4..+3 of row ln)
        floatx4 a[2];
        #pragma unroll
        for (int jj = 0; jj < 2; ++jj) {
            half2t lo = u2h2(xc[jj].x), hi = u2h2(xc[jj].y);
            a[jj] = floatx4{(float)lo[0], (float)lo[1], (float)hi[0], (float)hi[1]};
        }
        // 8 MFMAs, cc-major over 2 independent accumulators
        #pragma unroll
        for (int cc = 0; cc < 4; ++cc)
            #pragma unroll
            for (int jj = 0; jj < 2; ++jj)
                a[jj] = __builtin_amdgcn_mfma_f32_16x16x32_f16(wfr[jj][cc], hf[cc], a[jj], 0, 0, 0);
        // epilogue: relu + pack + routed partial dot
        uint2 hp[2];
        float p = 0.f;
        #pragma unroll
        for (int jj = 0; jj < 2; ++jj) {
            float r0 = fmaxf(a[jj][0], 0.f), r1 = fmaxf(a[jj][1], 0.f);
            float r2 = fmaxf(a[jj][2], 0.f), r3 = fmaxf(a[jj][3], 0.f);
            hp[jj].x = pkh(r0, r1);
            hp[jj].y = pkh(r2, r3);
            float4 wn4 = wnl[jj];
            p += r0 * wn4.x + r1 * wn4.y + r2 * wn4.z + r3 * wn4.w;
        }
        // build next-step B-frag chunk w from this wave's j-pair (2w, 2w+1)
        unsigned int ax = hp[0].x, bx = hp[1].x;
        pl32swap(ax, bx); pl16swap(ax, bx);   // ax=w0, bx=w2
        unsigned int ay = hp[0].y, by = hp[1].y;
        pl32swap(ay, by); pl16swap(ay, by);   // ay=w1, by=w3
        uint4v hw = {ax, ay, bx, by};
        hxch[par][w][l] = hw;
        // intra-wave p reduce over q (all lanes end with wave-partial)
        unsigned int pa = __builtin_bit_cast(unsigned int, p), pb = pa;
        pl32swap(pa, pb);
        float ps = __builtin_bit_cast(float, pa) + __builtin_bit_cast(float, pb);
        unsigned int pc = __builtin_bit_cast(unsigned int, ps), pd = pc;
        pl16swap(pc, pd);
        float ptot = __builtin_bit_cast(float, pc) + __builtin_bit_cast(float, pd);
        if (l < 16) pxch[par][w][ln] = ptot;
        // exchange: drain own DS writes, raw barrier (NO vmcnt drain)
        asm volatile("s_waitcnt lgkmcnt(0)" ::: "memory");
        __builtin_amdgcn_sched_barrier(0);
        __builtin_amdgcn_s_barrier();
        __builtin_amdgcn_sched_barrier(0);
        #pragma unroll
        for (int c = 0; c < 4; ++c)
            hf[c] = __builtin_bit_cast(half8, hxch[par][c][l]);
        // wave0: cross-wave p reduce + store
        if (w == 0) {
            float p2 = pxch[par][q][ln];
            unsigned int qa = __builtin_bit_cast(unsigned int, p2), qb = qa;
            pl32swap(qa, qb);
            float qs = __builtin_bit_cast(float, qa) + __builtin_bit_cast(float, qb);
            unsigned int qc = __builtin_bit_cast(unsigned int, qs), qd = qc;
            pl16swap(qc, qd);
            float qt = __builtin_bit_cast(float, qc) + __builtin_bit_cast(float, qd);
            if (l < 16) accp[t] = qt;
        }
    };

    ld(xb0, 0); ld(xb1, 1); ld(xb2, 2); ld(xb3, 3);
    for (int c = 0; c < T / 4 - 1; ++c) {
        int i0 = c * 4;
        step(xb0, i0);     ld(xb0, i0 + 4);
        step(xb1, i0 + 1); ld(xb1, i0 + 5);
        step(xb2, i0 + 2); ld(xb2, i0 + 6);
        step(xb3, i0 + 3); ld(xb3, i0 + 7);
    }
    step(xb0, T - 4);
    step(xb1, T - 3);
    step(xb2, T - 2);
    step(xb3, T - 1);
}

// ---------------- K4: out = relu(statd[b] + accf + accb) -> FP32 ------------
__global__ __launch_bounds__(256) void k_final(
    const float* __restrict__ statd, const float* __restrict__ accf,
    const float* __restrict__ accb, float* __restrict__ out)
{
    int idx = blockIdx.x * 256 + threadIdx.x;
    if (idx < BT) {
        int b = idx / T;
        out[idx] = fmaxf(statd[b] + accf[idx] + accb[idx], 0.f);
    }
}

extern "C" void kernel_launch(void* const* d_in, const int* in_sizes, int n_in,
                              void* d_out, int out_size, void* d_ws, size_t ws_size,
                              hipStream_t stream)
{
    const float* x_static  = (const float*)d_in[0];
    const float* x_dynamic = (const float*)d_in[1];
    const int*   norder    = (const int*)d_in[2];
    const float* w_s1   = (const float*)d_in[3];
    const float* b_s1   = (const float*)d_in[4];
    const float* w_s2   = (const float*)d_in[5];
    const float* b_s2   = (const float*)d_in[6];
    const float* w_dyn  = (const float*)d_in[7];
    const float* b_dyn  = (const float*)d_in[8];
    const float* w_ih_f = (const float*)d_in[9];
    const float* w_hh_f = (const float*)d_in[10];
    const float* b_ih_f = (const float*)d_in[11];
    const float* b_hh_f = (const float*)d_in[12];
    const float* w_ih_b = (const float*)d_in[13];
    const float* w_hh_b = (const float*)d_in[14];
    const float* b_ih_b = (const float*)d_in[15];
    const float* b_hh_b = (const float*)d_in[16];
    const float* nw     = (const float*)d_in[17];
    const float* nb     = (const float*)d_in[18];
    float* out = (float*)d_out;

    // ws: statd 2KB | accf 400KB | accb 400KB | xw fp16 52.4MB | prepped wts
    char* ws = (char*)d_ws;
    float* statd = (float*)ws;
    float* accf  = (float*)(ws + 2048);
    float* accb  = (float*)(ws + 2048 + (size_t)BT * 4);
    unsigned short* xw = (unsigned short*)(ws + 2048 + (size_t)BT * 8);
    size_t xw_bytes = (size_t)2 * BT * HD * 2;   // 52.4 MB
    unsigned short* wdyn_bf = (unsigned short*)(ws + 2048 + (size_t)BT * 8 + xw_bytes);
    unsigned short* wih_bf  = wdyn_bf + HD * 96;
    unsigned short* whh_h   = wih_bf + 2 * HD * HD;

    hipLaunchKernelGGL(k_prep, dim3(64), dim3(256), 0, stream,
                       w_dyn, w_ih_f, w_ih_b, w_hh_f, w_hh_b,
                       wdyn_bf, wih_bf, whh_h);
    hipLaunchKernelGGL(k_static, dim3(B), dim3(256), 0, stream,
                       x_static, w_s1, b_s1, w_s2, b_s2, norder, nw, nb, statd);
    hipLaunchKernelGGL(k_dxw, dim3(BT / 64), dim3(256), 0, stream,
                       x_dynamic, wdyn_bf, b_dyn, wih_bf,
                       b_ih_f, b_hh_f, b_ih_b, b_hh_b, xw);
    hipLaunchKernelGGL(k_scan, dim3(64), dim3(256), 0, stream,
                       xw, whh_h, norder, nw, accf, accb);
    hipLaunchKernelGGL(k_final, dim3((BT + 255) / 256), dim3(256), 0, stream,
                       statd, accf, accb, out);
}

// Round 8
// 299.226 us; speedup vs baseline: 1.4128x; 1.0570x over previous
//
#include <hip/hip_runtime.h>
#include <cstdint>

// MTNN: static MLP + dyn proj + biRNN(relu) + routed per-trial dot.
// B=512,T=200,SI=100,DI=68,HS=256,HD=128,D=512,K=1. fp32 in, fp32 out.
// R16 (passed, 316us total): k_scan 4-wave o-split -> ~80us, off top-5.
// R17: k_dxw was epilogue-bound (64 scalar 2B global stores + 32 scalar LDS
// writes + scalar staging per thread; MfmaUtil 3.3%, HBM 10% -> issue-bound).
// Fix: SWAP MFMA operands (A=weights, B=activations; frag layouts are
// symmetric) so C/D lane holds 4 CONSECUTIVE n for one batch row:
//   P2 dl write = 1 ds_write_b64 per j; P3 xw write = 1 uint2 global store
//   per j (coalesced 32B runs); bias via float4 (sums precomputed in k_prep);
//   staging via float4 loads + packed-bf16 b64 LDS writes.
constexpr int B = 512, T = 200, SI = 100, DI = 68, HS = 256, HD = 128, D = 512;
constexpr int BT = B * T;   // 102400

typedef __attribute__((ext_vector_type(8))) short short8;       // 8 bf16
typedef __attribute__((ext_vector_type(4))) float floatx4;      // MFMA C/D
typedef _Float16 half8 __attribute__((ext_vector_type(8)));     // 8 fp16
typedef _Float16 half2t __attribute__((ext_vector_type(2)));    // fp16 pair
typedef unsigned int uint2v __attribute__((ext_vector_type(2)));
typedef unsigned int uint4v __attribute__((ext_vector_type(4)));

#define DEV __device__ __forceinline__

DEV unsigned short f2bf(float f) {
    unsigned int x = __builtin_bit_cast(unsigned int, f);
    x += 0x7fffu + ((x >> 16) & 1u);   // RNE
    return (unsigned short)(x >> 16);
}
DEV unsigned int pkbf(float a, float b) {   // two bf16 in one dword
    return (unsigned int)f2bf(a) | ((unsigned int)f2bf(b) << 16);
}
DEV unsigned short f2h(float f) {
    return __builtin_bit_cast(unsigned short, (_Float16)f);
}
DEV half2t u2h2(unsigned int u) { return __builtin_bit_cast(half2t, u); }
DEV unsigned int pkh(float a, float b) {
    return __builtin_bit_cast(unsigned int, __builtin_amdgcn_cvt_pkrtz(a, b));
}
// gfx950 lane swaps (VALU). After p32: a=[a.lo,b.lo], b=[a.hi,b.hi].
// After p16 (per 32-half): a=[a.q0,b.q0|a.q2,b.q2], b=[a.q1,b.q1|a.q3,b.q3].
#if __has_builtin(__builtin_amdgcn_permlane32_swap) && __has_builtin(__builtin_amdgcn_permlane16_swap)
DEV void pl32swap(unsigned int& a, unsigned int& b) {
    uint2v r = __builtin_amdgcn_permlane32_swap(a, b, false, false);
    a = r[0]; b = r[1];
}
DEV void pl16swap(unsigned int& a, unsigned int& b) {
    uint2v r = __builtin_amdgcn_permlane16_swap(a, b, false, false);
    a = r[0]; b = r[1];
}
#else
DEV void pl32swap(unsigned int& a, unsigned int& b) {
    unsigned int na, nb;
    asm("v_mov_b32 %0, %2\n\t"
        "v_mov_b32 %1, %3\n\t"
        "v_permlane32_swap_b32 %0, %1"
        : "=&v"(na), "=&v"(nb) : "v"(a), "v"(b));
    a = na; b = nb;
}
DEV void pl16swap(unsigned int& a, unsigned int& b) {
    unsigned int na, nb;
    asm("v_mov_b32 %0, %2\n\t"
        "v_mov_b32 %1, %3\n\t"
        "v_permlane16_swap_b32 %0, %1"
        : "=&v"(na), "=&v"(nb) : "v"(a), "v"(b));
    a = na; b = nb;
}
#endif

// ---------------- K0: one-time weight conversion ----------------------------
// wdyn_bf[128][96] bf16 (zero-pad K 68->96) | wih_bf[2][128][128] bf16 |
// whh_h[2][128][128] fp16 | bsum[2][128] f32 (b_ih+b_hh)
__global__ __launch_bounds__(256) void k_prep(
    const float* __restrict__ wdyn,
    const float* __restrict__ wihf, const float* __restrict__ wihb,
    const float* __restrict__ whhf, const float* __restrict__ whhb,
    const float* __restrict__ bihf, const float* __restrict__ bhhf,
    const float* __restrict__ bihb, const float* __restrict__ bhhb,
    unsigned short* __restrict__ wdyn_bf, unsigned short* __restrict__ wih_bf,
    unsigned short* __restrict__ whh_h, float* __restrict__ bsum)
{
    int gid = blockIdx.x * 256 + threadIdx.x, gs = gridDim.x * 256;
    for (int i = gid; i < HD * 96; i += gs) {
        int r = i / 96, c = i - r * 96;
        wdyn_bf[i] = (c < DI) ? f2bf(wdyn[r * DI + c]) : 0;
    }
    for (int i = gid; i < 2 * HD * HD; i += gs) {
        const float* src = (i < HD * HD) ? wihf : wihb;
        wih_bf[i] = f2bf(src[i & (HD * HD - 1)]);
    }
    for (int i = gid; i < 2 * HD * HD; i += gs) {
        const float* src = (i < HD * HD) ? whhf : whhb;
        whh_h[i] = f2h(src[i & (HD * HD - 1)]);
    }
    for (int i = gid; i < 2 * HD; i += gs) {
        int z = i >> 7, n = i & (HD - 1);
        bsum[i] = z ? (bihb[n] + bhhb[n]) : (bihf[n] + bhhf[n]);
    }
}

// ---------------- K1: static branch + static segment of routed dot ----------
__global__ __launch_bounds__(256) void k_static(
    const float* __restrict__ xs_g, const float* __restrict__ w1,
    const float* __restrict__ b1, const float* __restrict__ w2,
    const float* __restrict__ b2, const int* __restrict__ norder,
    const float* __restrict__ nw, const float* __restrict__ nb,
    float* __restrict__ statd)
{
    __shared__ __align__(16) float xs[SI];
    __shared__ __align__(16) float s1[HS];
    __shared__ __align__(16) float red[256];
    int b = blockIdx.x, t = threadIdx.x;
    if (t < SI) xs[t] = xs_g[b * SI + t];
    __syncthreads();
    float a = b1[t];
    const float4* w = (const float4*)(w1 + t * SI);
    const float4* xp4 = (const float4*)xs;
    #pragma unroll
    for (int i = 0; i < SI / 4; ++i) {
        float4 ww = w[i]; float4 xx = xp4[i];
        a += xx.x * ww.x + xx.y * ww.y + xx.z * ww.z + xx.w * ww.w;
    }
    s1[t] = fmaxf(a, 0.f);
    __syncthreads();
    float a2 = b2[t];
    const float4* w2p = (const float4*)(w2 + t * HS);
    const float4* s1p = (const float4*)s1;
    #pragma unroll 8
    for (int i = 0; i < HS / 4; ++i) {
        float4 ww = w2p[i]; float4 s = s1p[i];
        a2 += s.x * ww.x + s.y * ww.y + s.z * ww.z + s.w * ww.w;
    }
    float sv = fmaxf(a2, 0.f);
    int n = norder[b];
    red[t] = sv * nw[(size_t)n * D + t];
    __syncthreads();
    for (int s = 128; s > 0; s >>= 1) {
        if (t < s) red[t] += red[t + s];
        __syncthreads();
    }
    if (t == 0) statd[b] = red[0] + nb[n];
}

// ---------------- K2: d + ih-projection via MFMA (operand-swapped) ----------
// A=weight rows n, B=activation rows batch -> C/D lane (ln,q) holds
// out[batch=w*16+ln][n=j*16+q*4+r], r=0..3 -> vector epilogues.
__global__ __launch_bounds__(256) void k_dxw(
    const float* __restrict__ xd,
    const unsigned short* __restrict__ wdyn_bf, const float* __restrict__ bdyn,
    const unsigned short* __restrict__ wih_bf, const float* __restrict__ bsum,
    unsigned short* __restrict__ xw)
{
    __shared__ __align__(16) unsigned short xb[64][104];  // x bf16, K 0..95 (+pad)
    __shared__ __align__(16) unsigned short dl[64][136];  // d bf16, 128 cols (+pad)
    int tid = threadIdx.x;
    int R0 = blockIdx.x * 64;
    // zero xb (vectorized 16B)
    for (int i = tid; i < 64 * 104 / 8; i += 256)
        ((uint4v*)xb)[i] = uint4v{0u, 0u, 0u, 0u};
    __syncthreads();
    // stage x: float4 loads, packed-bf16 b64 LDS writes (17 float4 per row)
    for (int i = tid; i < 64 * 17; i += 256) {
        int r = i / 17, c = i - r * 17;
        float4 v = *(const float4*)(xd + (size_t)(R0 + r) * DI + c * 4);
        uint2 pk;
        pk.x = pkbf(v.x, v.y);
        pk.y = pkbf(v.z, v.w);
        *(uint2*)&xb[r][c * 4] = pk;
    }
    __syncthreads();

    int lane = tid & 63, w = tid >> 6;
    int ln = lane & 15, q = lane >> 4;

    // ---- P2: A=wdyn[n][k], B=x[batch][k] ----
    short8 xf[3];
    #pragma unroll
    for (int c = 0; c < 3; ++c)
        xf[c] = *(const short8*)&xb[w * 16 + ln][c * 32 + q * 8];
    #pragma unroll
    for (int j = 0; j < 8; ++j) {
        floatx4 a = {0.f, 0.f, 0.f, 0.f};
        #pragma unroll
        for (int c = 0; c < 3; ++c) {
            short8 wf = *(const short8*)(wdyn_bf + (size_t)(j * 16 + ln) * 96 + c * 32 + q * 8);
            a = __builtin_amdgcn_mfma_f32_16x16x32_bf16(wf, xf[c], a, 0, 0, 0);
        }
        float4 bd4 = *(const float4*)(bdyn + j * 16 + q * 4);
        uint2 pk;
        pk.x = pkbf(fmaxf(a[0] + bd4.x, 0.f), fmaxf(a[1] + bd4.y, 0.f));
        pk.y = pkbf(fmaxf(a[2] + bd4.z, 0.f), fmaxf(a[3] + bd4.w, 0.f));
        *(uint2*)&dl[w * 16 + ln][j * 16 + q * 4] = pk;   // d[batch][n..n+3]
    }
    __syncthreads();

    // ---- P3 (both directions): A=wih[n][k], B=d[batch][k] ----
    short8 df[4];
    #pragma unroll
    for (int c = 0; c < 4; ++c)
        df[c] = *(const short8*)&dl[w * 16 + ln][c * 32 + q * 8];
    #pragma unroll
    for (int z = 0; z < 2; ++z) {
        const unsigned short* wih = wih_bf + (size_t)z * HD * HD;
        unsigned short* outp = xw + (size_t)z * BT * HD;
        int row = R0 + w * 16 + ln;
        #pragma unroll
        for (int j = 0; j < 8; ++j) {
            floatx4 a = {0.f, 0.f, 0.f, 0.f};
            #pragma unroll
            for (int c = 0; c < 4; ++c) {
                short8 wf = *(const short8*)(wih + (size_t)(j * 16 + ln) * HD + c * 32 + q * 8);
                a = __builtin_amdgcn_mfma_f32_16x16x32_bf16(wf, df[c], a, 0, 0, 0);
            }
            float4 b4 = *(const float4*)(bsum + z * HD + j * 16 + q * 4);
            uint2 hp;
            hp.x = (unsigned int)f2h(a[0] + b4.x) | ((unsigned int)f2h(a[1] + b4.y) << 16);
            hp.y = (unsigned int)f2h(a[2] + b4.z) | ((unsigned int)f2h(a[3] + b4.w) << 16);
            *(uint2*)(outp + (size_t)row * HD + j * 16 + q * 4) = hp;
        }
    }
}

// ---------------- K3: MFMA recurrence, 4-wave o-split -----------------------
// 64 blocks x 256 thr (4 waves). dir = bid>>5, b0 = (bid&31)*16.
// Wave w: o-tiles j=2w,2w+1 -> 8 MFMAs/step; produces next-step B-frag
// chunk w via permlane swaps; exchange through double-buffered LDS with raw
// s_barrier (no vmcnt drain). Routed-dot partials cross-wave via LDS.
__global__ __launch_bounds__(256, 1) void k_scan(
    const unsigned short* __restrict__ xw, const unsigned short* __restrict__ whh_h,
    const int* __restrict__ norder, const float* __restrict__ nw,
    float* __restrict__ accf, float* __restrict__ accb)
{
    __shared__ __align__(16) uint4v hxch[2][4][64];   // [parity][chunk][lane]
    __shared__ __align__(16) float  pxch[2][4][16];   // [parity][wave][row]

    int tid = threadIdx.x, w = tid >> 6, l = tid & 63, ln = l & 15, q = l >> 4;
    int dir = blockIdx.x >> 5, b0 = (blockIdx.x & 31) * 16;
    const unsigned short* whh = whh_h + (size_t)dir * HD * HD;
    float* acc = dir ? accb : accf;
    int segoff = dir ? (HS + HD) : HS;   // 384 : 256
    int j0 = 2 * w;                       // this wave's first o-tile

    half8 wfr[2][4];
    #pragma unroll
    for (int jj = 0; jj < 2; ++jj)
        #pragma unroll
        for (int c = 0; c < 4; ++c)
            wfr[jj][c] = *(const half8*)(whh + (size_t)((j0 + jj) * 16 + ln) * HD + c * 32 + q * 8);

    int nrow = norder[b0 + ln];
    float4 wnl[2];
    #pragma unroll
    for (int jj = 0; jj < 2; ++jj)
        wnl[jj] = *(const float4*)(nw + (size_t)nrow * D + segoff + (j0 + jj) * 16 + q * 4);

    half8 hf[4];
    uint4v zz = {0u, 0u, 0u, 0u};
    #pragma unroll
    for (int c = 0; c < 4; ++c) hf[c] = __builtin_bit_cast(half8, zz);

    const unsigned short* xp = xw + ((size_t)dir * BT + (size_t)(b0 + ln) * T) * HD;
    float* accp = acc + (size_t)(b0 + ln) * T;
    int tstart = dir ? (T - 1) : 0, dt = dir ? -1 : 1;

    uint2 xb0[2], xb1[2], xb2[2], xb3[2];
    auto ld = [&](uint2 (&xb)[2], int idx) {
        const unsigned short* pp = xp + (size_t)(tstart + dt * idx) * HD;
        #pragma unroll
        for (int jj = 0; jj < 2; ++jj)
            xb[jj] = *(const uint2*)(pp + (j0 + jj) * 16 + q * 4);
    };
    auto step = [&](uint2 (&xc)[2], int idx) {
        int t = tstart + dt * idx;
        int par = idx & 1;
        floatx4 a[2];
        #pragma unroll
        for (int jj = 0; jj < 2; ++jj) {
            half2t lo = u2h2(xc[jj].x), hi = u2h2(xc[jj].y);
            a[jj] = floatx4{(float)lo[0], (float)lo[1], (float)hi[0], (float)hi[1]};
        }
        #pragma unroll
        for (int cc = 0; cc < 4; ++cc)
            #pragma unroll
            for (int jj = 0; jj < 2; ++jj)
                a[jj] = __builtin_amdgcn_mfma_f32_16x16x32_f16(wfr[jj][cc], hf[cc], a[jj], 0, 0, 0);
        uint2 hp[2];
        float p = 0.f;
        #pragma unroll
        for (int jj = 0; jj < 2; ++jj) {
            float r0 = fmaxf(a[jj][0], 0.f), r1 = fmaxf(a[jj][1], 0.f);
            float r2 = fmaxf(a[jj][2], 0.f), r3 = fmaxf(a[jj][3], 0.f);
            hp[jj].x = pkh(r0, r1);
            hp[jj].y = pkh(r2, r3);
            float4 wn4 = wnl[jj];
            p += r0 * wn4.x + r1 * wn4.y + r2 * wn4.z + r3 * wn4.w;
        }
        unsigned int ax = hp[0].x, bx = hp[1].x;
        pl32swap(ax, bx); pl16swap(ax, bx);
        unsigned int ay = hp[0].y, by = hp[1].y;
        pl32swap(ay, by); pl16swap(ay, by);
        uint4v hw = {ax, ay, bx, by};
        hxch[par][w][l] = hw;
        unsigned int pa = __builtin_bit_cast(unsigned int, p), pb = pa;
        pl32swap(pa, pb);
        float ps = __builtin_bit_cast(float, pa) + __builtin_bit_cast(float, pb);
        unsigned int pc = __builtin_bit_cast(unsigned int, ps), pd = pc;
        pl16swap(pc, pd);
        float ptot = __builtin_bit_cast(float, pc) + __builtin_bit_cast(float, pd);
        if (l < 16) pxch[par][w][ln] = ptot;
        asm volatile("s_waitcnt lgkmcnt(0)" ::: "memory");
        __builtin_amdgcn_sched_barrier(0);
        __builtin_amdgcn_s_barrier();
        __builtin_amdgcn_sched_barrier(0);
        #pragma unroll
        for (int c = 0; c < 4; ++c)
            hf[c] = __builtin_bit_cast(half8, hxch[par][c][l]);
        if (w == 0) {
            float p2 = pxch[par][q][ln];
            unsigned int qa = __builtin_bit_cast(unsigned int, p2), qb = qa;
            pl32swap(qa, qb);
            float qs = __builtin_bit_cast(float, qa) + __builtin_bit_cast(float, qb);
            unsigned int qc = __builtin_bit_cast(unsigned int, qs), qd = qc;
            pl16swap(qc, qd);
            float qt = __builtin_bit_cast(float, qc) + __builtin_bit_cast(float, qd);
            if (l < 16) accp[t] = qt;
        }
    };

    ld(xb0, 0); ld(xb1, 1); ld(xb2, 2); ld(xb3, 3);
    for (int c = 0; c < T / 4 - 1; ++c) {
        int i0 = c * 4;
        step(xb0, i0);     ld(xb0, i0 + 4);
        step(xb1, i0 + 1); ld(xb1, i0 + 5);
        step(xb2, i0 + 2); ld(xb2, i0 + 6);
        step(xb3, i0 + 3); ld(xb3, i0 + 7);
    }
    step(xb0, T - 4);
    step(xb1, T - 3);
    step(xb2, T - 2);
    step(xb3, T - 1);
}

// ---------------- K4: out = relu(statd[b] + accf + accb) -> FP32 ------------
__global__ __launch_bounds__(256) void k_final(
    const float* __restrict__ statd, const float* __restrict__ accf,
    const float* __restrict__ accb, float* __restrict__ out)
{
    int idx = blockIdx.x * 256 + threadIdx.x;
    if (idx < BT) {
        int b = idx / T;
        out[idx] = fmaxf(statd[b] + accf[idx] + accb[idx], 0.f);
    }
}

extern "C" void kernel_launch(void* const* d_in, const int* in_sizes, int n_in,
                              void* d_out, int out_size, void* d_ws, size_t ws_size,
                              hipStream_t stream)
{
    const float* x_static  = (const float*)d_in[0];
    const float* x_dynamic = (const float*)d_in[1];
    const int*   norder    = (const int*)d_in[2];
    const float* w_s1   = (const float*)d_in[3];
    const float* b_s1   = (const float*)d_in[4];
    const float* w_s2   = (const float*)d_in[5];
    const float* b_s2   = (const float*)d_in[6];
    const float* w_dyn  = (const float*)d_in[7];
    const float* b_dyn  = (const float*)d_in[8];
    const float* w_ih_f = (const float*)d_in[9];
    const float* w_hh_f = (const float*)d_in[10];
    const float* b_ih_f = (const float*)d_in[11];
    const float* b_hh_f = (const float*)d_in[12];
    const float* w_ih_b = (const float*)d_in[13];
    const float* w_hh_b = (const float*)d_in[14];
    const float* b_ih_b = (const float*)d_in[15];
    const float* b_hh_b = (const float*)d_in[16];
    const float* nw     = (const float*)d_in[17];
    const float* nb     = (const float*)d_in[18];
    float* out = (float*)d_out;

    // ws: statd 2KB | accf 400KB | accb 400KB | xw fp16 52.4MB | prepped wts
    char* ws = (char*)d_ws;
    float* statd = (float*)ws;
    float* accf  = (float*)(ws + 2048);
    float* accb  = (float*)(ws + 2048 + (size_t)BT * 4);
    unsigned short* xw = (unsigned short*)(ws + 2048 + (size_t)BT * 8);
    size_t xw_bytes = (size_t)2 * BT * HD * 2;   // 52.4 MB
    unsigned short* wdyn_bf = (unsigned short*)(ws + 2048 + (size_t)BT * 8 + xw_bytes);
    unsigned short* wih_bf  = wdyn_bf + HD * 96;
    unsigned short* whh_h   = wih_bf + 2 * HD * HD;
    float* bsum = (float*)(whh_h + 2 * HD * HD);

    hipLaunchKernelGGL(k_prep, dim3(64), dim3(256), 0, stream,
                       w_dyn, w_ih_f, w_ih_b, w_hh_f, w_hh_b,
                       b_ih_f, b_hh_f, b_ih_b, b_hh_b,
                       wdyn_bf, wih_bf, whh_h, bsum);
    hipLaunchKernelGGL(k_static, dim3(B), dim3(256), 0, stream,
                       x_static, w_s1, b_s1, w_s2, b_s2, norder, nw, nb, statd);
    hipLaunchKernelGGL(k_dxw, dim3(BT / 64), dim3(256), 0, stream,
                       x_dynamic, wdyn_bf, b_dyn, wih_bf, bsum, xw);
    hipLaunchKernelGGL(k_scan, dim3(64), dim3(256), 0, stream,
                       xw, whh_h, norder, nw, accf, accb);
    hipLaunchKernelGGL(k_final, dim3((BT + 255) / 256), dim3(256), 0, stream,
                       statd, accf, accb, out);
}